// Round 1
// baseline (196.682 us; speedup 1.0000x reference)
//
#include <hip/hip_runtime.h>
#include <math.h>

#define TLEN 4096
#define NW 12
#define BLOCK 256
#define EPSF 1e-6f

// Full-wave (64-lane) sum.
__device__ __forceinline__ float wave_reduce_sum(float v) {
    #pragma unroll
    for (int o = 32; o > 0; o >>= 1) v += __shfl_xor(v, o, 64);
    return v;
}

// Thread-per-segment path (small w, many segments).
__device__ __forceinline__ void process_seq(const float* __restrict__ row, int w, int n,
                                            float* rs_sum, int k, int tid) {
    float acc = 0.0f;
    for (int s = tid; s < n; s += BLOCK) {
        const int b = s * w;
        const float a0 = row[b];
        const float m = (row[b + w - 1] - a0) / (float)(w - 1);
        float prev = a0;
        float vmax = -INFINITY, vmin = INFINITY, ss = 0.0f;
        for (int j = 1; j < w; ++j) {
            float val = row[b + j];
            float d = val - prev;
            ss = fmaf(d, d, ss);
            float v = fmaf((float)j, -m, val);   // val - j*m
            vmax = fmaxf(vmax, v);
            vmin = fminf(vmin, v);
            prev = val;
        }
        float var = (ss - (float)(w - 1) * m * m) / (float)(w - 2);
        float S = sqrtf(fmaxf(var, 0.0f));
        acc += (vmax - vmin) / (S + EPSF);
    }
    acc = wave_reduce_sum(acc);
    if ((tid & 63) == 0) atomicAdd(&rs_sum[k], acc);
}

// Lane-group-per-segment path. G is a power of two dividing 64.
template <int G>
__device__ __forceinline__ void process_grp(const float* __restrict__ row, int w, int n,
                                            float* rs_sum, int k, int tid) {
    const int gid = tid / G;
    const int lane = tid % G;
    const int ngroups = BLOCK / G;
    float acc = 0.0f;
    for (int s = gid; s < n; s += ngroups) {
        const int b = s * w;
        const float a0 = row[b];
        const float m = (row[b + w - 1] - a0) / (float)(w - 1);
        float vmax = -INFINITY, vmin = INFINITY, ss = 0.0f;
        float carry = a0;                         // row[b + i*G] seen by lane 0 next iter
        const int iters = (w - 1 + G - 1) / G;
        for (int i = 0; i < iters; ++i) {
            const int j = 1 + i * G + lane;
            const bool valid = (j < w);
            const int jj = valid ? j : (w - 1);   // clamp to stay in-bounds
            float val = row[b + jj];
            float prevv = __shfl_up(val, 1, G);
            if (lane == 0) prevv = carry;
            carry = __shfl(val, G - 1, G);
            if (valid) {
                float d = val - prevv;
                ss = fmaf(d, d, ss);
                float v = fmaf((float)j, -m, val);
                vmax = fmaxf(vmax, v);
                vmin = fminf(vmin, v);
            }
        }
        #pragma unroll
        for (int o = G / 2; o > 0; o >>= 1) {
            vmax = fmaxf(vmax, __shfl_xor(vmax, o, G));
            vmin = fminf(vmin, __shfl_xor(vmin, o, G));
            ss += __shfl_xor(ss, o, G);
        }
        if (lane == 0) {
            float var = (ss - (float)(w - 1) * m * m) / (float)(w - 2);
            float S = sqrtf(fmaxf(var, 0.0f));
            acc += (vmax - vmin) / (S + EPSF);
        }
    }
    acc = wave_reduce_sum(acc);
    if ((tid & 63) == 0) atomicAdd(&rs_sum[k], acc);
}

__global__ __launch_bounds__(BLOCK) void hurst_kernel(const float* __restrict__ x,
                                                      float* __restrict__ out) {
    __shared__ __align__(16) float row[TLEN];
    __shared__ float rs_sum[NW];
    const int tid = threadIdx.x;
    const int r = blockIdx.x;

    // One coalesced pass: 4096 floats via float4.
    const float4* src = (const float4*)(x + (size_t)r * TLEN);
    float4* dst = (float4*)row;
    #pragma unroll
    for (int i = 0; i < TLEN / 4 / BLOCK; ++i)
        dst[tid + i * BLOCK] = src[tid + i * BLOCK];
    if (tid < NW) rs_sum[tid] = 0.0f;
    __syncthreads();

    // ws = {10,17,31,56,100,177,316,562,1000,1778,3162,4096}; n = 4096/w
    process_seq    (row,   10, 409, rs_sum,  0, tid);
    process_seq    (row,   17, 240, rs_sum,  1, tid);
    process_seq    (row,   31, 132, rs_sum,  2, tid);
    process_grp<2> (row,   56,  73, rs_sum,  3, tid);
    process_grp<4> (row,  100,  40, rs_sum,  4, tid);
    process_grp<8> (row,  177,  23, rs_sum,  5, tid);
    process_grp<16>(row,  316,  12, rs_sum,  6, tid);
    process_grp<32>(row,  562,   7, rs_sum,  7, tid);
    process_grp<64>(row, 1000,   4, rs_sum,  8, tid);
    process_grp<64>(row, 1778,   2, rs_sum,  9, tid);
    process_grp<64>(row, 3162,   1, rs_sum, 10, tid);
    process_grp<64>(row, 4096,   1, rs_sum, 11, tid);

    __syncthreads();
    if (tid == 0) {
        const int ws[NW] = {10, 17, 31, 56, 100, 177, 316, 562, 1000, 1778, 3162, 4096};
        const int ns[NW] = {409, 240, 132, 73, 40, 23, 12, 7, 4, 2, 1, 1};
        double X[NW], Y[NW];
        double mx = 0.0, my = 0.0;
        #pragma unroll
        for (int i = 0; i < NW; ++i) {
            X[i] = log10((double)ws[i] + 1e-6);
            double rs = (double)rs_sum[i] / (double)ns[i];
            Y[i] = log10(rs + 1e-6);
            mx += X[i];
            my += Y[i];
        }
        mx /= NW;
        my /= NW;
        double num = 0.0, den = 0.0;
        #pragma unroll
        for (int i = 0; i < NW; ++i) {
            double xc = X[i] - mx;
            num += (Y[i] - my) * xc;
            den += xc * xc;
        }
        float h = (float)(num / (den + 1e-6));
        if (!isfinite(h)) h = 1.0f;
        out[r] = h;
    }
}

extern "C" void kernel_launch(void* const* d_in, const int* in_sizes, int n_in,
                              void* d_out, int out_size, void* d_ws, size_t ws_size,
                              hipStream_t stream) {
    const float* x = (const float*)d_in[0];
    float* out = (float*)d_out;
    const int B = out_size;  // 8192 rows
    hipLaunchKernelGGL(hurst_kernel, dim3(B), dim3(BLOCK), 0, stream, x, out);
}

// Round 2
// 151.644 us; speedup vs baseline: 1.2970x; 1.2970x over previous
//
#include <hip/hip_runtime.h>
#include <math.h>

#define TLEN 4096
#define NW   12
#define BLOCK 256
#define EPSF 1e-6f

// Centered log10(w+1e-6) values (sum = 0) and 1/n_segments, precomputed in double.
__device__ const float XC_TAB[NW] = {
    -1.3608041f, -1.1303552f, -0.8694424f, -0.6126161f,
    -0.3608041f, -0.1128308f,  0.1388830f,  0.3889322f,
     0.6391959f,  0.8891277f,  1.1391578f,  1.2515558f };
__device__ const float INVN_TAB[NW] = {
    1.0f/409.0f, 1.0f/240.0f, 1.0f/132.0f, 1.0f/73.0f,
    1.0f/40.0f,  1.0f/23.0f,  1.0f/12.0f,  1.0f/7.0f,
    0.25f, 0.5f, 1.0f, 1.0f };
// 1/(sum(XC^2) + 1e-6)
#define INV_DEN 0.11577579f

__device__ __forceinline__ float wave_reduce_sum(float v) {
    #pragma unroll
    for (int o = 32; o > 0; o >>= 1) v += __shfl_xor(v, o, 64);
    return v;
}

// P[i] = sum_{k<i} d[k]^2, reconstructed from even-index table P2 (P2[e] = P[2e]).
__device__ __forceinline__ float prefP(const float* __restrict__ row,
                                       const float* __restrict__ P2, int i) {
    float p = P2[i >> 1];
    if (i & 1) {
        float d = row[i] - row[i - 1];
        p = fmaf(d, d, p);
    }
    return p;
}

__device__ __forceinline__ float seg_rs(const float* __restrict__ row,
                                        const float* __restrict__ P2,
                                        int b, int W, float m, float invwm2,
                                        float vmax, float vmin) {
    float ss  = prefP(row, P2, b + W - 1) - prefP(row, P2, b);
    float var = (ss - (float)(W - 1) * m * m) * invwm2;
    float S   = sqrtf(fmaxf(var, 0.0f));
    return (vmax - vmin) / (S + EPSF);
}

// Thread-per-segment (small W). Scalar loads (odd strides are conflict-free).
template<int W>
__device__ __forceinline__ void win_seq(const float* __restrict__ row,
                                        const float* __restrict__ P2,
                                        float* __restrict__ rs_sum, int k, int tid) {
    constexpr int N = TLEN / W;
    constexpr float invwm1 = 1.0f / (float)(W - 1);
    constexpr float invwm2 = 1.0f / (float)(W - 2);
    float acc = 0.0f;
    for (int s = tid; s < N; s += BLOCK) {
        const int b = s * W;
        const float m  = (row[b + W - 1] - row[b]) * invwm1;
        const float nm = -m;
        float vmax = -INFINITY, vmin = INFINITY;
        #pragma unroll
        for (int j = 1; j < W; ++j) {
            float v = fmaf((float)j, nm, row[b + j]);
            vmax = fmaxf(vmax, v);
            vmin = fminf(vmin, v);
        }
        acc += seg_rs(row, P2, b, W, m, invwm2, vmax, vmin);
    }
    acc = wave_reduce_sum(acc);
    if ((tid & 63) == 0) atomicAdd(&rs_sum[k], acc);
}

// Lane-group-per-segment (mid W). Aligned float4 main body + scalar pre/tail.
template<int W, int G>
__device__ __forceinline__ void win_grp(const float* __restrict__ row,
                                        const float* __restrict__ P2,
                                        float* __restrict__ rs_sum, int k, int tid) {
    constexpr int N  = TLEN / W;
    constexpr int NG = BLOCK / G;
    constexpr float invwm1 = 1.0f / (float)(W - 1);
    constexpr float invwm2 = 1.0f / (float)(W - 2);
    const int lane = tid & (G - 1);
    const int gid  = tid / G;
    float acc = 0.0f;
    for (int s = gid; s < N; s += NG) {
        const int b = s * W;
        const float m  = (row[b + W - 1] - row[b]) * invwm1;
        const float nm = -m;
        float vmax = -INFINITY, vmin = INFINITY;
        const int first = 4 - (b & 3);          // 1..4 ; (b+first)%4 == 0
        for (int j = 1 + lane; j < first; j += G) {
            float v = fmaf((float)j, nm, row[b + j]);
            vmax = fmaxf(vmax, v); vmin = fminf(vmin, v);
        }
        const int nmain = (W - first) >> 2;
        const int tail  = (W - first) & 3;
        const float4* __restrict__ vp = (const float4*)(row + b + first);
        for (int c = lane; c < nmain; c += G) {
            float4 q = vp[c];
            float jb = (float)(first + 4 * c);
            float v0 = fmaf(jb,        nm, q.x);
            float v1 = fmaf(jb + 1.f,  nm, q.y);
            float v2 = fmaf(jb + 2.f,  nm, q.z);
            float v3 = fmaf(jb + 3.f,  nm, q.w);
            vmax = fmaxf(vmax, fmaxf(fmaxf(v0, v1), fmaxf(v2, v3)));
            vmin = fminf(vmin, fminf(fminf(v0, v1), fminf(v2, v3)));
        }
        for (int j = W - tail + lane; j < W; j += G) {
            float v = fmaf((float)j, nm, row[b + j]);
            vmax = fmaxf(vmax, v); vmin = fminf(vmin, v);
        }
        #pragma unroll
        for (int o = G >> 1; o > 0; o >>= 1) {
            vmax = fmaxf(vmax, __shfl_xor(vmax, o, G));
            vmin = fminf(vmin, __shfl_xor(vmin, o, G));
        }
        if (lane == 0) acc += seg_rs(row, P2, b, W, m, invwm2, vmax, vmin);
    }
    acc = wave_reduce_sum(acc);
    if ((tid & 63) == 0) atomicAdd(&rs_sum[k], acc);
}

// Whole-block-per-segment (largest W): full utilization, LDS cross-wave reduce.
template<int W>
__device__ __forceinline__ void win_blk(const float* __restrict__ row,
                                        const float* __restrict__ P2,
                                        float* __restrict__ rs_sum,
                                        float* __restrict__ wred, int k, int tid) {
    constexpr int N = TLEN / W;
    constexpr float invwm1 = 1.0f / (float)(W - 1);
    constexpr float invwm2 = 1.0f / (float)(W - 2);
    #pragma unroll
    for (int s = 0; s < N; ++s) {
        const int b = s * W;
        const float m  = (row[b + W - 1] - row[b]) * invwm1;
        const float nm = -m;
        float vmax = -INFINITY, vmin = INFINITY;
        const int first = 4 - (b & 3);
        for (int j = 1 + tid; j < first; j += BLOCK) {
            float v = fmaf((float)j, nm, row[b + j]);
            vmax = fmaxf(vmax, v); vmin = fminf(vmin, v);
        }
        const int nmain = (W - first) >> 2;
        const int tail  = (W - first) & 3;
        const float4* __restrict__ vp = (const float4*)(row + b + first);
        for (int c = tid; c < nmain; c += BLOCK) {
            float4 q = vp[c];
            float jb = (float)(first + 4 * c);
            float v0 = fmaf(jb,        nm, q.x);
            float v1 = fmaf(jb + 1.f,  nm, q.y);
            float v2 = fmaf(jb + 2.f,  nm, q.z);
            float v3 = fmaf(jb + 3.f,  nm, q.w);
            vmax = fmaxf(vmax, fmaxf(fmaxf(v0, v1), fmaxf(v2, v3)));
            vmin = fminf(vmin, fminf(fminf(v0, v1), fminf(v2, v3)));
        }
        for (int j = W - tail + tid; j < W; j += BLOCK) {
            float v = fmaf((float)j, nm, row[b + j]);
            vmax = fmaxf(vmax, v); vmin = fminf(vmin, v);
        }
        #pragma unroll
        for (int o = 32; o > 0; o >>= 1) {
            vmax = fmaxf(vmax, __shfl_xor(vmax, o, 64));
            vmin = fminf(vmin, __shfl_xor(vmin, o, 64));
        }
        const int wid = tid >> 6;
        if ((tid & 63) == 0) { wred[2 * wid] = vmax; wred[2 * wid + 1] = vmin; }
        __syncthreads();
        if (tid == 0) {
            float mx = fmaxf(fmaxf(wred[0], wred[2]), fmaxf(wred[4], wred[6]));
            float mn = fminf(fminf(wred[1], wred[3]), fminf(wred[5], wred[7]));
            atomicAdd(&rs_sum[k], seg_rs(row, P2, b, W, m, invwm2, mx, mn));
        }
        __syncthreads();
    }
}

__global__ __launch_bounds__(BLOCK) void hurst_kernel(const float* __restrict__ x,
                                                      float* __restrict__ out) {
    __shared__ __align__(16) float row[TLEN];
    __shared__ __align__(16) float P2[TLEN / 2];
    __shared__ float rs_sum[NW];
    __shared__ float wred[8];

    const int tid = threadIdx.x;
    const int r = blockIdx.x;

    // One coalesced HBM pass per row.
    const float4* src = (const float4*)(x + (size_t)r * TLEN);
    float4* dst = (float4*)row;
    #pragma unroll
    for (int i = 0; i < TLEN / 4 / BLOCK; ++i)
        dst[tid + i * BLOCK] = src[tid + i * BLOCK];
    if (tid < NW) rs_sum[tid] = 0.0f;
    __syncthreads();

    // ---- Build P2: prefix sums of squared adjacent diffs, stored at even indices ----
    {
        const int base = tid * 16;
        float v[17];
        const float4* rp = (const float4*)(row + base);
        float4 q0 = rp[0], q1 = rp[1], q2 = rp[2], q3 = rp[3];
        v[0]=q0.x;  v[1]=q0.y;  v[2]=q0.z;  v[3]=q0.w;
        v[4]=q1.x;  v[5]=q1.y;  v[6]=q1.z;  v[7]=q1.w;
        v[8]=q2.x;  v[9]=q2.y;  v[10]=q2.z; v[11]=q2.w;
        v[12]=q3.x; v[13]=q3.y; v[14]=q3.z; v[15]=q3.w;
        v[16] = row[(base + 16 < TLEN) ? base + 16 : TLEN - 1];  // t=255: d=0, unused

        float pl[8];
        float c = 0.0f;
        #pragma unroll
        for (int j = 0; j < 16; ++j) {
            if ((j & 1) == 0) pl[j >> 1] = c;
            float d = v[j + 1] - v[j];
            c = fmaf(d, d, c);
        }
        const float total = c;
        const int lane = tid & 63, wid = tid >> 6;
        float incl = total;
        #pragma unroll
        for (int o = 1; o < 64; o <<= 1) {
            float u = __shfl_up(incl, o, 64);
            if (lane >= o) incl += u;
        }
        if (lane == 63) wred[wid] = incl;
        __syncthreads();
        float off = incl - total;  // exclusive within wave
        #pragma unroll
        for (int w2 = 0; w2 < 4; ++w2)
            if (w2 < wid) off += wred[w2];
        float4* pp = (float4*)(P2 + tid * 8);
        pp[0] = make_float4(off + pl[0], off + pl[1], off + pl[2], off + pl[3]);
        pp[1] = make_float4(off + pl[4], off + pl[5], off + pl[6], off + pl[7]);
    }
    __syncthreads();

    // ws = {10,17,31,56,100,177,316,562,1000,1778,3162,4096}
    win_seq<10>          (row, P2, rs_sum, 0, tid);
    win_seq<17>          (row, P2, rs_sum, 1, tid);
    win_seq<31>          (row, P2, rs_sum, 2, tid);
    win_grp<56, 8>       (row, P2, rs_sum, 3, tid);
    win_grp<100, 16>     (row, P2, rs_sum, 4, tid);
    win_grp<177, 32>     (row, P2, rs_sum, 5, tid);
    win_grp<316, 64>     (row, P2, rs_sum, 6, tid);
    win_grp<562, 64>     (row, P2, rs_sum, 7, tid);
    win_grp<1000, 64>    (row, P2, rs_sum, 8, tid);
    win_blk<1778>        (row, P2, rs_sum, wred, 9, tid);
    win_blk<3162>        (row, P2, rs_sum, wred, 10, tid);
    win_blk<4096>        (row, P2, rs_sum, wred, 11, tid);

    __syncthreads();
    // H = sum_i log10(RS_i + eps) * XC_i / (sum XC^2 + eps)   (centered X => mean term drops)
    if (tid < 64) {
        float t = 0.0f;
        if (tid < NW)
            t = log10f(fmaf(rs_sum[tid], INVN_TAB[tid], EPSF)) * XC_TAB[tid];
        t = wave_reduce_sum(t);
        if (tid == 0) {
            float h = t * INV_DEN;
            if (!isfinite(h)) h = 1.0f;
            out[r] = h;
        }
    }
}

extern "C" void kernel_launch(void* const* d_in, const int* in_sizes, int n_in,
                              void* d_out, int out_size, void* d_ws, size_t ws_size,
                              hipStream_t stream) {
    const float* x = (const float*)d_in[0];
    float* out = (float*)d_out;
    const int B = out_size;  // 8192 rows
    hipLaunchKernelGGL(hurst_kernel, dim3(B), dim3(BLOCK), 0, stream, x, out);
}

// Round 3
// 106.184 us; speedup vs baseline: 1.8523x; 1.4281x over previous
//
#include <hip/hip_runtime.h>
#include <math.h>
#include <utility>

#define TLEN 4096
#define NW   12
#define BLOCK 256
#define EPSF 1e-6f

// Centered log10(w+1e-6) values (sum = 0) and 1/n_segments, precomputed in double.
__device__ const float XC_TAB[NW] = {
    -1.3608041f, -1.1303552f, -0.8694424f, -0.6126161f,
    -0.3608041f, -0.1128308f,  0.1388830f,  0.3889322f,
     0.6391959f,  0.8891277f,  1.1391578f,  1.2515558f };
__device__ const float INVN_TAB[NW] = {
    1.0f/409.0f, 1.0f/240.0f, 1.0f/132.0f, 1.0f/73.0f,
    1.0f/40.0f,  1.0f/23.0f,  1.0f/12.0f,  1.0f/7.0f,
    0.25f, 0.5f, 1.0f, 1.0f };
#define INV_DEN 0.11577579f

__device__ __forceinline__ float max3f(float a, float b, float c) {
    float r; asm("v_max3_f32 %0, %1, %2, %3" : "=v"(r) : "v"(a), "v"(b), "v"(c)); return r;
}
__device__ __forceinline__ float min3f(float a, float b, float c) {
    float r; asm("v_min3_f32 %0, %1, %2, %3" : "=v"(r) : "v"(a), "v"(b), "v"(c)); return r;
}

__device__ __forceinline__ float wave_reduce_sum(float v) {
    #pragma unroll
    for (int o = 32; o > 0; o >>= 1) v += __shfl_xor(v, o, 64);
    return v;
}

// P[i] = sum_{k<i} d[k]^2 reconstructed from even-index table P2 (P2[e] = P[2e]).
__device__ __forceinline__ float prefP(const float* __restrict__ row,
                                       const float* __restrict__ P2, int i) {
    float p = P2[i >> 1];
    if (i & 1) {
        float d = row[i] - row[i - 1];
        p = fmaf(d, d, p);
    }
    return p;
}

__device__ __forceinline__ float seg_rs(const float* __restrict__ row,
                                        const float* __restrict__ P2,
                                        int b, int W, float m, float invwm2,
                                        float vmax, float vmin) {
    float ss  = prefP(row, P2, b + W - 1) - prefP(row, P2, b);
    float var = (ss - (float)(W - 1) * m * m) * invwm2;
    float S   = sqrtf(fmaxf(var, 0.0f));
    return (vmax - vmin) / (S + EPSF);
}

// Fold slots LO..HI of chunk q (j of slot r = JB + r, compile-time) into mx/mn.
template<int LO, int HI, int JB>
__device__ __forceinline__ void chunk_fold(const float4 q, float nm, float& mx, float& mn) {
    if constexpr (LO <= HI) {
        constexpr int NV = HI - LO + 1;
        float v[NV];
        #pragma unroll
        for (int r = 0; r < NV; ++r)
            v[r] = fmaf((float)(JB + LO + r), nm, (&q.x)[LO + r]);
        if constexpr (NV == 1) { mx = fmaxf(mx, v[0]); mn = fminf(mn, v[0]); }
        else if constexpr (NV == 2) { mx = max3f(mx, v[0], v[1]); mn = min3f(mn, v[0], v[1]); }
        else if constexpr (NV == 3) { mx = fmaxf(mx, max3f(v[0], v[1], v[2]));
                                      mn = fminf(mn, min3f(v[0], v[1], v[2])); }
        else { mx = max3f(max3f(mx, v[0], v[1]), v[2], v[3]);
               mn = min3f(min3f(mn, v[0], v[1]), v[2], v[3]); }
    }
}

// ---- Multi-segment aligned tasks (thread-per-task, small W) ----
// Task = NSEG consecutive segments starting at 16B-aligned b. All slot->segment
// mapping and j values are compile-time.
template<int W, int NSEG, int C>
__device__ __forceinline__ void mchunk_step(const float4* __restrict__ p,
                                            const float (&nm)[NSEG],
                                            float (&mx)[NSEG], float (&mn)[NSEG]) {
    constexpr int E0 = 4 * C;
    constexpr int K0 = E0 / W;
    constexpr int SA = K0 * W;
    constexpr int LOA = (SA == E0) ? 1 : 0;          // exclude j=0 slot
    constexpr int HIA_ = SA + W - 1 - E0;
    constexpr int HIA = HIA_ < 3 ? HIA_ : 3;
    float4 q = p[C];
    if constexpr (K0 < NSEG)
        chunk_fold<LOA, HIA, E0 - SA>(q, nm[K0], mx[K0], mn[K0]);
    constexpr bool HASB = (K0 + 1 < NSEG) && (SA + W + 1 - E0 <= 3);
    if constexpr (HASB) {
        constexpr int SB = SA + W;
        chunk_fold<SB + 1 - E0, 3, E0 - SB>(q, nm[K0 + 1], mx[K0 + 1], mn[K0 + 1]);
    }
}

template<int W, int NSEG, int... Cs>
__device__ __forceinline__ void mseg_all(const float4* __restrict__ p,
                                         const float (&nm)[NSEG],
                                         float (&mx)[NSEG], float (&mn)[NSEG],
                                         std::integer_sequence<int, Cs...>) {
    (mchunk_step<W, NSEG, Cs>(p, nm, mx, mn), ...);
}

template<int W, int NSEG>
__device__ __forceinline__ float mseg_task(const float* __restrict__ row,
                                           const float* __restrict__ P2, int b) {
    constexpr int NCH = (W * NSEG + 3) / 4;
    const float4* p = (const float4*)(row + b);
    float nm[NSEG], m[NSEG], mx[NSEG], mn[NSEG];
    #pragma unroll
    for (int k = 0; k < NSEG; ++k) {
        float a0 = row[b + k * W];
        float a1 = row[b + k * W + W - 1];
        m[k] = (a1 - a0) * (1.0f / (float)(W - 1));
        nm[k] = -m[k];
        mx[k] = -INFINITY; mn[k] = INFINITY;
    }
    mseg_all<W, NSEG>(p, nm, mx, mn, std::make_integer_sequence<int, NCH>{});
    float acc = 0.0f;
    #pragma unroll
    for (int k = 0; k < NSEG; ++k)
        acc += seg_rs(row, P2, b + k * W, W, m[k], 1.0f / (float)(W - 2), mx[k], mn[k]);
    return acc;
}

// ---- Strided single-segment processing: G lanes cover chunks of one segment ----
// A = b & 3 (compile-time variant). Full chunks 1..NFULL handled by lane-strided
// unrolled loop (static LDS offsets); boundary chunks by lanes 0/1.
template<int W, int A, int G>
__device__ __forceinline__ void seg_strided(const float* __restrict__ row, int b, int lane,
                                            float nm, float& mx, float& mn) {
    constexpr int NCH  = (A + W - 1) / 4 + 1;
    constexpr int HIL  = (A + W - 1) & 3;
    constexpr int MAIN_END = (HIL == 3) ? NCH : NCH - 1;
    constexpr int NFULL = MAIN_END - 1;
    constexpr int ITERS = (NFULL + G - 1) / G;
    const float4* p = (const float4*)(row + (b - A));
    mx = -INFINITY; mn = INFINITY;
    const float4* pl = p + (1 + lane);
    float jf = (float)(4 * (1 + lane) - A);
    #pragma unroll
    for (int i = 0; i < ITERS; ++i) {
        bool ok = (i < ITERS - 1) || (1 + lane + i * G <= NFULL);
        if (ok) {
            float4 q = pl[i * G];
            float v0 = fmaf(jf,        nm, q.x);
            float v1 = fmaf(jf + 1.0f, nm, q.y);
            float v2 = fmaf(jf + 2.0f, nm, q.z);
            float v3 = fmaf(jf + 3.0f, nm, q.w);
            mx = max3f(max3f(mx, v0, v1), v2, v3);
            mn = min3f(min3f(mn, v0, v1), v2, v3);
        }
        jf += (float)(4 * G);
    }
    if constexpr (A < 3) {
        if (lane == 0) chunk_fold<A + 1, 3, -A>(p[0], nm, mx, mn);
    }
    if constexpr (HIL != 3) {
        if (lane == 1) chunk_fold<0, HIL, 4 * (NCH - 1) - A>(p[NCH - 1], nm, mx, mn);
    }
}

// group of G lanes -> one segment; returns rs contribution on lane 0, else 0.
template<int W, int A, int G>
__device__ __forceinline__ float group_seg(const float* __restrict__ row,
                                           const float* __restrict__ P2,
                                           int s, int lane) {
    const int b = s * W;
    float a0 = row[b], a1 = row[b + W - 1];
    float m = (a1 - a0) * (1.0f / (float)(W - 1));
    float nm = -m;
    float mx, mn;
    seg_strided<W, A, G>(row, b, lane, nm, mx, mn);
    #pragma unroll
    for (int o = G / 2; o > 0; o >>= 1) {
        mx = fmaxf(mx, __shfl_xor(mx, o, G));
        mn = fminf(mn, __shfl_xor(mn, o, G));
    }
    return (lane == 0) ? seg_rs(row, P2, b, W, m, 1.0f / (float)(W - 2), mx, mn) : 0.0f;
}

__global__ __launch_bounds__(BLOCK) void hurst_kernel(const float* __restrict__ x,
                                                      float* __restrict__ out) {
    __shared__ __align__(16) float row[TLEN];
    __shared__ __align__(16) float P2[TLEN / 2];
    __shared__ float rs_sum[NW];
    __shared__ float wred[8];

    const int tid = threadIdx.x;
    const int r = blockIdx.x;
    const int w = tid >> 6, l = tid & 63;

    // One coalesced HBM pass per row.
    const float4* src = (const float4*)(x + (size_t)r * TLEN);
    float4* dst = (float4*)row;
    #pragma unroll
    for (int i = 0; i < TLEN / 4 / BLOCK; ++i)
        dst[tid + i * BLOCK] = src[tid + i * BLOCK];
    if (tid < NW) rs_sum[tid] = 0.0f;
    __syncthreads();

    // ---- Build P2: prefix sums of squared adjacent diffs at even indices ----
    {
        const int base = tid * 16;
        float v[17];
        const float4* rp = (const float4*)(row + base);
        float4 q0 = rp[0], q1 = rp[1], q2 = rp[2], q3 = rp[3];
        v[0]=q0.x;  v[1]=q0.y;  v[2]=q0.z;  v[3]=q0.w;
        v[4]=q1.x;  v[5]=q1.y;  v[6]=q1.z;  v[7]=q1.w;
        v[8]=q2.x;  v[9]=q2.y;  v[10]=q2.z; v[11]=q2.w;
        v[12]=q3.x; v[13]=q3.y; v[14]=q3.z; v[15]=q3.w;
        v[16] = row[(base + 16 < TLEN) ? base + 16 : TLEN - 1];

        float pl[8];
        float c = 0.0f;
        #pragma unroll
        for (int j = 0; j < 16; ++j) {
            if ((j & 1) == 0) pl[j >> 1] = c;
            float d = v[j + 1] - v[j];
            c = fmaf(d, d, c);
        }
        const float total = c;
        float incl = total;
        #pragma unroll
        for (int o = 1; o < 64; o <<= 1) {
            float u = __shfl_up(incl, o, 64);
            if (l >= o) incl += u;
        }
        if (l == 63) wred[w] = incl;
        __syncthreads();
        float off = incl - total;
        #pragma unroll
        for (int w2 = 0; w2 < 4; ++w2)
            if (w2 < w) off += wred[w2];
        float4* pp = (float4*)(P2 + tid * 8);
        pp[0] = make_float4(off + pl[0], off + pl[1], off + pl[2], off + pl[3]);
        pp[1] = make_float4(off + pl[4], off + pl[5], off + pl[6], off + pl[7]);
    }
    __syncthreads();

    // ================= wave phase (no __syncthreads inside) =================

    // W=10 (idx 0): 204 pair-tasks + 1 solo, all 16B-aligned.
    {
        float a = 0.0f;
        if (tid < 204)       a = mseg_task<10, 2>(row, P2, tid * 20);
        else if (tid == 204) a = mseg_task<10, 1>(row, P2, 4080);
        a = wave_reduce_sum(a);
        if (l == 0) atomicAdd(&rs_sum[0], a);
    }
    // W=17 (idx 1) on wave 0; W=31 (idx 2) on wave 1 (concurrent).
    if (w == 0) {
        float a = (l < 60) ? mseg_task<17, 4>(row, P2, l * 68) : 0.0f;
        a = wave_reduce_sum(a);
        if (l == 0) atomicAdd(&rs_sum[1], a);
    } else if (w == 1) {
        float a = (l < 33) ? mseg_task<31, 4>(row, P2, l * 124) : 0.0f;
        a = wave_reduce_sum(a);
        if (l == 0) atomicAdd(&rs_sum[2], a);
    }
    // W=56 (idx 3): G=4, 73 segs.
    {
        const int g = tid >> 2, gl = tid & 3;
        float a = group_seg<56, 0, 4>(row, P2, g, gl);
        if (g + 64 < 73) a += group_seg<56, 0, 4>(row, P2, g + 64, gl);
        a = wave_reduce_sum(a);
        if (l == 0) atomicAdd(&rs_sum[3], a);
    }
    // W=100 (idx 4): G=8, 40 segs.
    {
        const int g = tid >> 3, gl = tid & 7;
        float a = group_seg<100, 0, 8>(row, P2, g, gl);
        if (g + 32 < 40) a += group_seg<100, 0, 8>(row, P2, g + 32, gl);
        a = wave_reduce_sum(a);
        if (l == 0) atomicAdd(&rs_sum[4], a);
    }
    // W=177 (idx 5): G=16; segment classes by s&3 == b&3 -> one alignment per wave.
    {
        const int g4 = (tid >> 4) & 3, gl16 = tid & 15;
        float a = 0.0f;
        if (w == 0) {
            a = group_seg<177, 0, 16>(row, P2, 4 * g4, gl16);
            if (g4 < 2) a += group_seg<177, 0, 16>(row, P2, 4 * (g4 + 4), gl16);
        } else if (w == 1) {
            a = group_seg<177, 1, 16>(row, P2, 4 * g4 + 1, gl16);
            if (g4 < 2) a += group_seg<177, 1, 16>(row, P2, 4 * (g4 + 4) + 1, gl16);
        } else if (w == 2) {
            a = group_seg<177, 2, 16>(row, P2, 4 * g4 + 2, gl16);
            if (g4 < 2) a += group_seg<177, 2, 16>(row, P2, 4 * (g4 + 4) + 2, gl16);
        } else {
            a = group_seg<177, 3, 16>(row, P2, 4 * g4 + 3, gl16);
            if (g4 < 1) a += group_seg<177, 3, 16>(row, P2, 4 * (g4 + 4) + 3, gl16);
        }
        a = wave_reduce_sum(a);
        if (l == 0) atomicAdd(&rs_sum[5], a);
    }
    // W=316 (idx 6): G=16, 12 segs on waves 0-2.
    if (tid < 192) {
        float a = group_seg<316, 0, 16>(row, P2, tid >> 4, tid & 15);
        a = wave_reduce_sum(a);
        if (l == 0) atomicAdd(&rs_sum[6], a);
    }
    // W=562 (idx 7): G=32; parity classes per wave (even s: A=0, odd s: A=2).
    {
        const int gh = (tid >> 5) & 1, gl32 = tid & 31;
        float a = 0.0f;
        if (w == 0)      a = group_seg<562, 0, 32>(row, P2, 0 + 2 * gh, gl32);
        else if (w == 1) a = group_seg<562, 0, 32>(row, P2, 4 + 2 * gh, gl32);
        else if (w == 2) a = group_seg<562, 2, 32>(row, P2, 1 + 2 * gh, gl32);
        else if (gh == 0) a = group_seg<562, 2, 32>(row, P2, 5, gl32);
        a = wave_reduce_sum(a);
        if (l == 0) atomicAdd(&rs_sum[7], a);
    }
    // W=1000 (idx 8): G=32, 4 segs on waves 0-1.
    if (tid < 128) {
        float a = group_seg<1000, 0, 32>(row, P2, tid >> 5, tid & 31);
        a = wave_reduce_sum(a);
        if (l == 0) atomicAdd(&rs_sum[8], a);
    }

    // ================= block phase =================

    // W=1778 (idx 9): waves {0,1} -> seg0 (A=0), waves {2,3} -> seg1 (A=2).
    {
        const int half = tid >> 7, hl = tid & 127;
        const int b = half ? 1778 : 0;
        float m = (row[b + 1777] - row[b]) * (1.0f / 1777.0f);
        float nm = -m, mx, mn;
        if (half == 0) seg_strided<1778, 0, 128>(row, 0,    hl, nm, mx, mn);
        else           seg_strided<1778, 2, 128>(row, 1778, hl, nm, mx, mn);
        #pragma unroll
        for (int o = 32; o > 0; o >>= 1) {
            mx = fmaxf(mx, __shfl_xor(mx, o, 64));
            mn = fminf(mn, __shfl_xor(mn, o, 64));
        }
        if (l == 0) { wred[w * 2] = mx; wred[w * 2 + 1] = mn; }
        __syncthreads();
        if ((tid & 127) == 0) {
            const int wb = tid >> 6;  // 0 or 2
            float MX = fmaxf(wred[wb * 2],     wred[wb * 2 + 2]);
            float MN = fminf(wred[wb * 2 + 1], wred[wb * 2 + 3]);
            atomicAdd(&rs_sum[9], seg_rs(row, P2, b, 1778, m, 1.0f / 1776.0f, MX, MN));
        }
        __syncthreads();
    }
    // W=3162 (idx 10): whole block, 1 segment.
    {
        float m = (row[3161] - row[0]) * (1.0f / 3161.0f);
        float nm = -m, mx, mn;
        seg_strided<3162, 0, 256>(row, 0, tid, nm, mx, mn);
        #pragma unroll
        for (int o = 32; o > 0; o >>= 1) {
            mx = fmaxf(mx, __shfl_xor(mx, o, 64));
            mn = fminf(mn, __shfl_xor(mn, o, 64));
        }
        if (l == 0) { wred[w * 2] = mx; wred[w * 2 + 1] = mn; }
        __syncthreads();
        if (tid == 0) {
            float MX = fmaxf(fmaxf(wred[0], wred[2]), fmaxf(wred[4], wred[6]));
            float MN = fminf(fminf(wred[1], wred[3]), fminf(wred[5], wred[7]));
            atomicAdd(&rs_sum[10], seg_rs(row, P2, 0, 3162, m, 1.0f / 3160.0f, MX, MN));
        }
        __syncthreads();
    }
    // W=4096 (idx 11): whole block, 1 segment.
    {
        float m = (row[4095] - row[0]) * (1.0f / 4095.0f);
        float nm = -m, mx, mn;
        seg_strided<4096, 0, 256>(row, 0, tid, nm, mx, mn);
        #pragma unroll
        for (int o = 32; o > 0; o >>= 1) {
            mx = fmaxf(mx, __shfl_xor(mx, o, 64));
            mn = fminf(mn, __shfl_xor(mn, o, 64));
        }
        if (l == 0) { wred[w * 2] = mx; wred[w * 2 + 1] = mn; }
        __syncthreads();
        if (tid == 0) {
            float MX = fmaxf(fmaxf(wred[0], wred[2]), fmaxf(wred[4], wred[6]));
            float MN = fminf(fminf(wred[1], wred[3]), fminf(wred[5], wred[7]));
            atomicAdd(&rs_sum[11], seg_rs(row, P2, 0, 4096, m, 1.0f / 4094.0f, MX, MN));
        }
        __syncthreads();
    }

    // ================= epilogue =================
    if (tid < 64) {
        float t = 0.0f;
        if (tid < NW)
            t = log10f(fmaf(rs_sum[tid], INVN_TAB[tid], EPSF)) * XC_TAB[tid];
        t = wave_reduce_sum(t);
        if (tid == 0) {
            float h = t * INV_DEN;
            if (!isfinite(h)) h = 1.0f;
            out[r] = h;
        }
    }
}

extern "C" void kernel_launch(void* const* d_in, const int* in_sizes, int n_in,
                              void* d_out, int out_size, void* d_ws, size_t ws_size,
                              hipStream_t stream) {
    const float* x = (const float*)d_in[0];
    float* out = (float*)d_out;
    const int B = out_size;  // 8192 rows
    hipLaunchKernelGGL(hurst_kernel, dim3(B), dim3(BLOCK), 0, stream, x, out);
}

// Round 4
// 93.069 us; speedup vs baseline: 2.1133x; 1.1409x over previous
//
#include <hip/hip_runtime.h>
#include <math.h>
#include <utility>

#define TLEN 4096
#define NW   12
#define BLOCK 256
#define EPSF 1e-6f

typedef float v2f __attribute__((ext_vector_type(2)));

// Centered log10(w+1e-6) values (sum = 0) and 1/n_segments, precomputed in double.
__device__ const float XC_TAB[NW] = {
    -1.3608041f, -1.1303552f, -0.8694424f, -0.6126161f,
    -0.3608041f, -0.1128308f,  0.1388830f,  0.3889322f,
     0.6391959f,  0.8891277f,  1.1391578f,  1.2515558f };
__device__ const float INVN_TAB[NW] = {
    1.0f/409.0f, 1.0f/240.0f, 1.0f/132.0f, 1.0f/73.0f,
    1.0f/40.0f,  1.0f/23.0f,  1.0f/12.0f,  1.0f/7.0f,
    0.25f, 0.5f, 1.0f, 1.0f };
#define INV_DEN 0.11577579f
#define LOG10_2 0.30102999566f

__device__ __forceinline__ float max3f(float a, float b, float c) {
    float r; asm("v_max3_f32 %0, %1, %2, %3" : "=v"(r) : "v"(a), "v"(b), "v"(c)); return r;
}
__device__ __forceinline__ float min3f(float a, float b, float c) {
    float r; asm("v_min3_f32 %0, %1, %2, %3" : "=v"(r) : "v"(a), "v"(b), "v"(c)); return r;
}
__device__ __forceinline__ v2f pk_fma(v2f a, v2f b, v2f c) {
    v2f d; asm("v_pk_fma_f32 %0, %1, %2, %3" : "=v"(d) : "v"(a), "v"(b), "v"(c)); return d;
}
__device__ __forceinline__ v2f pk_add(v2f a, v2f b) {
    v2f d; asm("v_pk_add_f32 %0, %1, %2" : "=v"(d) : "v"(a), "v"(b)); return d;
}

__device__ __forceinline__ float wave_reduce_sum(float v) {
    #pragma unroll
    for (int o = 32; o > 0; o >>= 1) v += __shfl_xor(v, o, 64);
    return v;
}
// Sum when only lanes == 0 (mod G) hold nonzero values.
template<int G>
__device__ __forceinline__ float reduce_leaders(float v) {
    #pragma unroll
    for (int o = G; o < 64; o <<= 1) v += __shfl_xor(v, o, 64);
    return v;  // lane 0 holds the wave total
}

// R/S for one segment; prefix-parity fixups resolved at compile time.
template<bool FIX_LO, bool FIX_HI>
__device__ __forceinline__ float seg_rs2(const float* __restrict__ row,
                                         const float* __restrict__ P2,
                                         int b, int W, float m, float invwm2,
                                         float mx, float mn) {
    float plo = P2[b >> 1];
    if constexpr (FIX_LO) { float d = row[b] - row[b - 1]; plo = fmaf(d, d, plo); }
    float phi = P2[(b + W - 1) >> 1];
    if constexpr (FIX_HI) { float d = row[b + W - 1] - row[b + W - 2]; phi = fmaf(d, d, phi); }
    float ss  = phi - plo;
    float var = fmaf(-(float)(W - 1) * m, m, ss) * invwm2;
    float S   = __builtin_amdgcn_sqrtf(fmaxf(var, 0.0f));
    return (mx - mn) * __builtin_amdgcn_rcpf(S + EPSF);
}

// Fold slots LO..HI of chunk q (j of slot r = JB + r, compile-time) into mx/mn.
template<int LO, int HI, int JB>
__device__ __forceinline__ void chunk_fold(const float4 q, float nm, float& mx, float& mn) {
    if constexpr (LO <= HI) {
        constexpr int NV = HI - LO + 1;
        float v[NV];
        #pragma unroll
        for (int r = 0; r < NV; ++r)
            v[r] = fmaf((float)(JB + LO + r), nm, (&q.x)[LO + r]);
        if constexpr (NV == 1) { mx = fmaxf(mx, v[0]); mn = fminf(mn, v[0]); }
        else if constexpr (NV == 2) { mx = max3f(mx, v[0], v[1]); mn = min3f(mn, v[0], v[1]); }
        else if constexpr (NV == 3) { mx = fmaxf(mx, max3f(v[0], v[1], v[2]));
                                      mn = fminf(mn, min3f(v[0], v[1], v[2])); }
        else { mx = max3f(max3f(mx, v[0], v[1]), v[2], v[3]);
               mn = min3f(min3f(mn, v[0], v[1]), v[2], v[3]); }
    }
}

// ---- W=10 hand path: pair task (2 segs, 5 preloaded chunks, all-register) ----
__device__ __forceinline__ float w10_task(const float* __restrict__ row,
                                          const float* __restrict__ P2,
                                          int t, bool pair) {
    const int b = t * 20;
    const int h = b >> 1;
    const float4* p = (const float4*)(row + b);
    float4 q0 = p[0], q1 = p[1], q2 = p[2];
    float acc;
    {
        const float m = (q2.y - q0.x) * (1.0f / 9.0f), nm = -m;
        float v1 = fmaf(1.0f, nm, q0.y);
        float v2 = fmaf(2.0f, nm, q0.z);
        float v3 = fmaf(3.0f, nm, q0.w);
        float mx = max3f(v1, v2, v3), mn = min3f(v1, v2, v3);
        float v4 = fmaf(4.0f, nm, q1.x);
        float v5 = fmaf(5.0f, nm, q1.y);
        float v6 = fmaf(6.0f, nm, q1.z);
        float v7 = fmaf(7.0f, nm, q1.w);
        mx = max3f(mx, v4, v5); mn = min3f(mn, v4, v5);
        mx = max3f(mx, v6, v7); mn = min3f(mn, v6, v7);
        float v8 = fmaf(8.0f, nm, q2.x);
        float v9 = fmaf(9.0f, nm, q2.y);
        mx = max3f(mx, v8, v9); mn = min3f(mn, v8, v9);
        float d9 = q2.y - q2.x;
        float ss = fmaf(d9, d9, P2[h + 4]) - P2[h];
        float var = fmaf(-9.0f * m, m, ss) * 0.125f;
        float S = __builtin_amdgcn_sqrtf(fmaxf(var, 0.0f));
        acc = (mx - mn) * __builtin_amdgcn_rcpf(S + EPSF);
    }
    if (pair) {
        float4 q3 = p[3], q4 = p[4];
        const float m = (q4.w - q2.z) * (1.0f / 9.0f), nm = -m;
        float v1 = fmaf(1.0f, nm, q2.w);
        float v2 = fmaf(2.0f, nm, q3.x);
        float v3 = fmaf(3.0f, nm, q3.y);
        float mx = max3f(v1, v2, v3), mn = min3f(v1, v2, v3);
        float v4 = fmaf(4.0f, nm, q3.z);
        float v5 = fmaf(5.0f, nm, q3.w);
        float v6 = fmaf(6.0f, nm, q4.x);
        float v7 = fmaf(7.0f, nm, q4.y);
        mx = max3f(mx, v4, v5); mn = min3f(mn, v4, v5);
        mx = max3f(mx, v6, v7); mn = min3f(mn, v6, v7);
        float v8 = fmaf(8.0f, nm, q4.z);
        float v9 = fmaf(9.0f, nm, q4.w);
        mx = max3f(mx, v8, v9); mn = min3f(mn, v8, v9);
        float d9 = q4.w - q4.z;
        float ss = fmaf(d9, d9, P2[h + 9]) - P2[h + 5];
        float var = fmaf(-9.0f * m, m, ss) * 0.125f;
        float S = __builtin_amdgcn_sqrtf(fmaxf(var, 0.0f));
        acc += (mx - mn) * __builtin_amdgcn_rcpf(S + EPSF);
    }
    return acc;
}

// ---- Multi-segment aligned tasks (odd W, base 16B-aligned) ----
template<int W, int NSEG, int C>
__device__ __forceinline__ void mchunk_step(const float4* __restrict__ p,
                                            const float (&nm)[NSEG],
                                            float (&mx)[NSEG], float (&mn)[NSEG]) {
    constexpr int E0 = 4 * C;
    constexpr int K0 = E0 / W;
    constexpr int SA = K0 * W;
    constexpr int LOA = (SA == E0) ? 1 : 0;
    constexpr int HIA_ = SA + W - 1 - E0;
    constexpr int HIA = HIA_ < 3 ? HIA_ : 3;
    float4 q = p[C];
    if constexpr (K0 < NSEG)
        chunk_fold<LOA, HIA, E0 - SA>(q, nm[K0], mx[K0], mn[K0]);
    constexpr bool HASB = (K0 + 1 < NSEG) && (SA + W + 1 - E0 <= 3);
    if constexpr (HASB) {
        constexpr int SB = SA + W;
        chunk_fold<SB + 1 - E0, 3, E0 - SB>(q, nm[K0 + 1], mx[K0 + 1], mn[K0 + 1]);
    }
}

template<int W, int NSEG, int... Cs>
__device__ __forceinline__ void mseg_all(const float4* __restrict__ p,
                                         const float (&nm)[NSEG],
                                         float (&mx)[NSEG], float (&mn)[NSEG],
                                         std::integer_sequence<int, Cs...>) {
    (mchunk_step<W, NSEG, Cs>(p, nm, mx, mn), ...);
}

// Odd W, b = task*const with const % 4 == 0 -> seg k parity = k&1 (compile-time).
template<int W, int NSEG>
__device__ __forceinline__ float mseg_task_odd(const float* __restrict__ row,
                                               const float* __restrict__ P2, int b) {
    constexpr int NCH = (W * NSEG + 3) / 4;
    constexpr float invwm2 = 1.0f / (float)(W - 2);
    const float4* p = (const float4*)(row + b);
    float nm[NSEG], m[NSEG], mx[NSEG], mn[NSEG];
    #pragma unroll
    for (int k = 0; k < NSEG; ++k) {
        float a0 = row[b + k * W];
        float a1 = row[b + k * W + W - 1];
        m[k] = (a1 - a0) * (1.0f / (float)(W - 1));
        nm[k] = -m[k];
        mx[k] = -INFINITY; mn[k] = INFINITY;
    }
    mseg_all<W, NSEG>(p, nm, mx, mn, std::make_integer_sequence<int, NCH>{});
    float acc = 0.0f;
    #pragma unroll
    for (int k = 0; k < NSEG; ++k) {
        float r = (k & 1)
            ? seg_rs2<true,  true >(row, P2, b + k * W, W, m[k], invwm2, mx[k], mn[k])
            : seg_rs2<false, false>(row, P2, b + k * W, W, m[k], invwm2, mx[k], mn[k]);
        acc += r;
    }
    return acc;
}

// ---- Packed strided single-segment bulk: G lanes cover chunks of one segment ----
template<int W, int A, int G>
__device__ __forceinline__ void seg_strided_pk(const float* __restrict__ row, int b, int lane,
                                               float nm, float& mx, float& mn) {
    constexpr int NCH  = (A + W - 1) / 4 + 1;
    constexpr int HIL  = (A + W - 1) & 3;
    constexpr int MAIN_END = (HIL == 3) ? NCH : NCH - 1;
    constexpr int NFULL = MAIN_END - 1;           // full chunks are 1..NFULL
    constexpr int FULL  = NFULL / G;
    constexpr int REM   = NFULL % G;
    const float4* p = (const float4*)(row + (b - A));
    mx = -INFINITY; mn = INFINITY;
    const float4* pl = p + (1 + lane);
    v2f jc; jc.x = (float)(4 * (1 + lane) - A); jc.y = jc.x + 1.0f;
    const v2f nm2   = {nm, nm};
    const v2f nm2x2 = {nm + nm, nm + nm};
    const v2f step  = {(float)(4 * G), (float)(4 * G)};
    #pragma unroll
    for (int i = 0; i < FULL; ++i) {
        float4 q = pl[i * G];
        v2f q01 = {q.x, q.y}, q23 = {q.z, q.w};
        v2f t01 = pk_fma(jc, nm2, q01);
        v2f t23 = pk_fma(jc, nm2, pk_add(q23, nm2x2));
        mx = max3f(max3f(mx, t01.x, t01.y), t23.x, t23.y);
        mn = min3f(min3f(mn, t01.x, t01.y), t23.x, t23.y);
        jc = pk_add(jc, step);
    }
    if constexpr (REM > 0) {
        if (lane < REM) {
            float4 q = pl[FULL * G];
            v2f q01 = {q.x, q.y}, q23 = {q.z, q.w};
            v2f t01 = pk_fma(jc, nm2, q01);
            v2f t23 = pk_fma(jc, nm2, pk_add(q23, nm2x2));
            mx = max3f(max3f(mx, t01.x, t01.y), t23.x, t23.y);
            mn = min3f(min3f(mn, t01.x, t01.y), t23.x, t23.y);
        }
    }
    if constexpr (A < 3) {
        if (lane == 0) chunk_fold<A + 1, 3, -A>(p[0], nm, mx, mn);
    }
    if constexpr (HIL != 3) {
        if (lane == 1) chunk_fold<0, HIL, 4 * (NCH - 1) - A>(p[NCH - 1], nm, mx, mn);
    }
}

// Group of G lanes -> one segment; rs contribution on lane 0 of the group.
template<int W, int A, int G>
__device__ __forceinline__ float group_seg(const float* __restrict__ row,
                                           const float* __restrict__ P2,
                                           int s, int lane) {
    const int b = s * W;
    float a0 = row[b], a1 = row[b + W - 1];
    float m = (a1 - a0) * (1.0f / (float)(W - 1));
    float nm = -m;
    float mx, mn;
    seg_strided_pk<W, A, G>(row, b, lane, nm, mx, mn);
    #pragma unroll
    for (int o = G / 2; o > 0; o >>= 1) {
        mx = fmaxf(mx, __shfl_xor(mx, o, G));
        mn = fminf(mn, __shfl_xor(mn, o, G));
    }
    float r = seg_rs2<(A & 1) != 0, ((A + W - 1) & 1) != 0>(
        row, P2, b, W, m, 1.0f / (float)(W - 2), mx, mn);
    return (lane == 0) ? r : 0.0f;
}

__global__ __launch_bounds__(BLOCK) void hurst_kernel(const float* __restrict__ x,
                                                      float* __restrict__ out) {
    __shared__ __align__(16) float row[TLEN];
    __shared__ __align__(16) float P2[TLEN / 2];
    __shared__ float rs_sum[NW];
    __shared__ float wred[8];

    const int tid = threadIdx.x;
    const int r = blockIdx.x;
    const int w = tid >> 6, l = tid & 63;

    // One coalesced HBM pass per row.
    const float4* src = (const float4*)(x + (size_t)r * TLEN);
    float4* dst = (float4*)row;
    #pragma unroll
    for (int i = 0; i < TLEN / 4 / BLOCK; ++i)
        dst[tid + i * BLOCK] = src[tid + i * BLOCK];
    if (tid < NW) rs_sum[tid] = 0.0f;
    __syncthreads();

    // ---- Build P2: prefix sums of squared adjacent diffs at even indices ----
    {
        const int base = tid * 16;
        float v[17];
        const float4* rp = (const float4*)(row + base);
        float4 q0 = rp[0], q1 = rp[1], q2 = rp[2], q3 = rp[3];
        v[0]=q0.x;  v[1]=q0.y;  v[2]=q0.z;  v[3]=q0.w;
        v[4]=q1.x;  v[5]=q1.y;  v[6]=q1.z;  v[7]=q1.w;
        v[8]=q2.x;  v[9]=q2.y;  v[10]=q2.z; v[11]=q2.w;
        v[12]=q3.x; v[13]=q3.y; v[14]=q3.z; v[15]=q3.w;
        v[16] = row[(base + 16 < TLEN) ? base + 16 : TLEN - 1];

        float pl[8];
        float c = 0.0f;
        #pragma unroll
        for (int j = 0; j < 16; ++j) {
            if ((j & 1) == 0) pl[j >> 1] = c;
            float d = v[j + 1] - v[j];
            c = fmaf(d, d, c);
        }
        const float total = c;
        float incl = total;
        #pragma unroll
        for (int o = 1; o < 64; o <<= 1) {
            float u = __shfl_up(incl, o, 64);
            if (l >= o) incl += u;
        }
        if (l == 63) wred[w] = incl;
        __syncthreads();
        float off = incl - total;
        #pragma unroll
        for (int w2 = 0; w2 < 4; ++w2)
            if (w2 < w) off += wred[w2];
        float4* pp = (float4*)(P2 + tid * 8);
        pp[0] = make_float4(off + pl[0], off + pl[1], off + pl[2], off + pl[3]);
        pp[1] = make_float4(off + pl[4], off + pl[5], off + pl[6], off + pl[7]);
    }
    __syncthreads();

    // ================= wave phase (no __syncthreads inside) =================

    // W=10 (idx 0): 204 pair-tasks + 1 solo, all register-resident.
    {
        float a = 0.0f;
        if (tid < 204)       a = w10_task(row, P2, tid, true);
        else if (tid == 204) a = w10_task(row, P2, 204, false);
        a = wave_reduce_sum(a);
        if (l == 0) atomicAdd(&rs_sum[0], a);
    }
    // W=17 (idx 1) on wave 0; W=31 (idx 2) on wave 1 (concurrent).
    if (w == 0) {
        float a = (l < 60) ? mseg_task_odd<17, 4>(row, P2, l * 68) : 0.0f;
        a = wave_reduce_sum(a);
        if (l == 0) atomicAdd(&rs_sum[1], a);
    } else if (w == 1) {
        float a = (l < 33) ? mseg_task_odd<31, 4>(row, P2, l * 124) : 0.0f;
        a = wave_reduce_sum(a);
        if (l == 0) atomicAdd(&rs_sum[2], a);
    }
    // W=56 (idx 3): G=4, 73 segs.
    {
        const int g = tid >> 2, gl = tid & 3;
        float a = group_seg<56, 0, 4>(row, P2, g, gl);
        if (g + 64 < 73) a += group_seg<56, 0, 4>(row, P2, g + 64, gl);
        a = reduce_leaders<4>(a);
        if (l == 0) atomicAdd(&rs_sum[3], a);
    }
    // W=100 (idx 4): G=8, 40 segs.
    {
        const int g = tid >> 3, gl = tid & 7;
        float a = group_seg<100, 0, 8>(row, P2, g, gl);
        if (g + 32 < 40) a += group_seg<100, 0, 8>(row, P2, g + 32, gl);
        a = reduce_leaders<8>(a);
        if (l == 0) atomicAdd(&rs_sum[4], a);
    }
    // W=177 (idx 5): G=16; alignment class A = s&3 mapped per wave.
    {
        const int g4 = (tid >> 4) & 3, gl16 = tid & 15;
        float a = 0.0f;
        if (w == 0) {
            a = group_seg<177, 0, 16>(row, P2, 4 * g4, gl16);
            if (g4 < 2) a += group_seg<177, 0, 16>(row, P2, 4 * (g4 + 4), gl16);
        } else if (w == 1) {
            a = group_seg<177, 1, 16>(row, P2, 4 * g4 + 1, gl16);
            if (g4 < 2) a += group_seg<177, 1, 16>(row, P2, 4 * (g4 + 4) + 1, gl16);
        } else if (w == 2) {
            a = group_seg<177, 2, 16>(row, P2, 4 * g4 + 2, gl16);
            if (g4 < 2) a += group_seg<177, 2, 16>(row, P2, 4 * (g4 + 4) + 2, gl16);
        } else {
            a = group_seg<177, 3, 16>(row, P2, 4 * g4 + 3, gl16);
            if (g4 < 1) a += group_seg<177, 3, 16>(row, P2, 4 * (g4 + 4) + 3, gl16);
        }
        a = reduce_leaders<16>(a);
        if (l == 0) atomicAdd(&rs_sum[5], a);
    }
    // W=316 (idx 6): G=16, 12 segs on waves 0-2.
    if (tid < 192) {
        float a = group_seg<316, 0, 16>(row, P2, tid >> 4, tid & 15);
        a = reduce_leaders<16>(a);
        if (l == 0) atomicAdd(&rs_sum[6], a);
    }
    // W=562 (idx 7): G=32; even s -> A=0 (waves 0,1), odd s -> A=2 (waves 2,3).
    {
        const int gh = (tid >> 5) & 1, gl32 = tid & 31;
        float a = 0.0f;
        if (w == 0)      a = group_seg<562, 0, 32>(row, P2, 0 + 2 * gh, gl32);
        else if (w == 1) a = group_seg<562, 0, 32>(row, P2, 4 + 2 * gh, gl32);
        else if (w == 2) a = group_seg<562, 2, 32>(row, P2, 1 + 2 * gh, gl32);
        else if (gh == 0) a = group_seg<562, 2, 32>(row, P2, 5, gl32);
        a = reduce_leaders<32>(a);
        if (l == 0) atomicAdd(&rs_sum[7], a);
    }
    // W=1000 (idx 8): G=32, 4 segs on waves 0-1.
    if (tid < 128) {
        float a = group_seg<1000, 0, 32>(row, P2, tid >> 5, tid & 31);
        a = reduce_leaders<32>(a);
        if (l == 0) atomicAdd(&rs_sum[8], a);
    }

    // ================= block phase =================

    // W=1778 (idx 9): waves {0,1} -> seg0 (A=0), waves {2,3} -> seg1 (A=2).
    {
        const int half = tid >> 7, hl = tid & 127;
        const int b = half ? 1778 : 0;
        float m = (row[b + 1777] - row[b]) * (1.0f / 1777.0f);
        float nm = -m, mx, mn;
        if (half == 0) seg_strided_pk<1778, 0, 128>(row, 0,    hl, nm, mx, mn);
        else           seg_strided_pk<1778, 2, 128>(row, 1778, hl, nm, mx, mn);
        #pragma unroll
        for (int o = 32; o > 0; o >>= 1) {
            mx = fmaxf(mx, __shfl_xor(mx, o, 64));
            mn = fminf(mn, __shfl_xor(mn, o, 64));
        }
        if (l == 0) { wred[w * 2] = mx; wred[w * 2 + 1] = mn; }
        __syncthreads();
        if ((tid & 127) == 0) {
            const int wb = tid >> 6;  // 0 or 2
            float MX = fmaxf(wred[wb * 2],     wred[wb * 2 + 2]);
            float MN = fminf(wred[wb * 2 + 1], wred[wb * 2 + 3]);
            atomicAdd(&rs_sum[9],
                      seg_rs2<false, true>(row, P2, b, 1778, m, 1.0f / 1776.0f, MX, MN));
        }
        __syncthreads();
    }
    // W=3162 (idx 10): whole block, 1 segment.
    {
        float m = (row[3161] - row[0]) * (1.0f / 3161.0f);
        float nm = -m, mx, mn;
        seg_strided_pk<3162, 0, 256>(row, 0, tid, nm, mx, mn);
        #pragma unroll
        for (int o = 32; o > 0; o >>= 1) {
            mx = fmaxf(mx, __shfl_xor(mx, o, 64));
            mn = fminf(mn, __shfl_xor(mn, o, 64));
        }
        if (l == 0) { wred[w * 2] = mx; wred[w * 2 + 1] = mn; }
        __syncthreads();
        if (tid == 0) {
            float MX = fmaxf(fmaxf(wred[0], wred[2]), fmaxf(wred[4], wred[6]));
            float MN = fminf(fminf(wred[1], wred[3]), fminf(wred[5], wred[7]));
            atomicAdd(&rs_sum[10],
                      seg_rs2<false, true>(row, P2, 0, 3162, m, 1.0f / 3160.0f, MX, MN));
        }
        __syncthreads();
    }
    // W=4096 (idx 11): whole block, 1 segment.
    {
        float m = (row[4095] - row[0]) * (1.0f / 4095.0f);
        float nm = -m, mx, mn;
        seg_strided_pk<4096, 0, 256>(row, 0, tid, nm, mx, mn);
        #pragma unroll
        for (int o = 32; o > 0; o >>= 1) {
            mx = fmaxf(mx, __shfl_xor(mx, o, 64));
            mn = fminf(mn, __shfl_xor(mn, o, 64));
        }
        if (l == 0) { wred[w * 2] = mx; wred[w * 2 + 1] = mn; }
        __syncthreads();
        if (tid == 0) {
            float MX = fmaxf(fmaxf(wred[0], wred[2]), fmaxf(wred[4], wred[6]));
            float MN = fminf(fminf(wred[1], wred[3]), fminf(wred[5], wred[7]));
            atomicAdd(&rs_sum[11],
                      seg_rs2<false, true>(row, P2, 0, 4096, m, 1.0f / 4094.0f, MX, MN));
        }
        __syncthreads();
    }

    // ================= epilogue =================
    if (tid < 64) {
        float t = 0.0f;
        if (tid < NW) {
            float rs = fmaf(rs_sum[tid], INVN_TAB[tid], EPSF);
            t = __builtin_amdgcn_logf(rs) * (LOG10_2) * XC_TAB[tid];
        }
        t = wave_reduce_sum(t);
        if (tid == 0) {
            float h = t * INV_DEN;
            if (!isfinite(h)) h = 1.0f;
            out[r] = h;
        }
    }
}

extern "C" void kernel_launch(void* const* d_in, const int* in_sizes, int n_in,
                              void* d_out, int out_size, void* d_ws, size_t ws_size,
                              hipStream_t stream) {
    const float* x = (const float*)d_in[0];
    float* out = (float*)d_out;
    const int B = out_size;  // 8192 rows
    hipLaunchKernelGGL(hurst_kernel, dim3(B), dim3(BLOCK), 0, stream, x, out);
}

// Round 5
// 90.055 us; speedup vs baseline: 2.1840x; 1.0335x over previous
//
#include <hip/hip_runtime.h>
#include <math.h>
#include <utility>

#define TLEN 4096
#define NW   12
#define BLOCK 256
#define EPSF 1e-6f

typedef float v2f __attribute__((ext_vector_type(2)));

// Centered log10(w+1e-6) values (sum = 0) and 1/n_segments, precomputed in double.
__device__ const float XC_TAB[NW] = {
    -1.3608041f, -1.1303552f, -0.8694424f, -0.6126161f,
    -0.3608041f, -0.1128308f,  0.1388830f,  0.3889322f,
     0.6391959f,  0.8891277f,  1.1391578f,  1.2515558f };
__device__ const float INVN_TAB[NW] = {
    1.0f/409.0f, 1.0f/240.0f, 1.0f/132.0f, 1.0f/73.0f,
    1.0f/40.0f,  1.0f/23.0f,  1.0f/12.0f,  1.0f/7.0f,
    0.25f, 0.5f, 1.0f, 1.0f };
#define INV_DEN 0.11577579f
#define LOG10_2 0.30102999566f

__device__ __forceinline__ float max3f(float a, float b, float c) {
    float r; asm("v_max3_f32 %0, %1, %2, %3" : "=v"(r) : "v"(a), "v"(b), "v"(c)); return r;
}
__device__ __forceinline__ float min3f(float a, float b, float c) {
    float r; asm("v_min3_f32 %0, %1, %2, %3" : "=v"(r) : "v"(a), "v"(b), "v"(c)); return r;
}
__device__ __forceinline__ v2f pk_fma(v2f a, v2f b, v2f c) {
    v2f d; asm("v_pk_fma_f32 %0, %1, %2, %3" : "=v"(d) : "v"(a), "v"(b), "v"(c)); return d;
}
__device__ __forceinline__ v2f pk_add(v2f a, v2f b) {
    v2f d; asm("v_pk_add_f32 %0, %1, %2" : "=v"(d) : "v"(a), "v"(b)); return d;
}

__device__ __forceinline__ float wave_reduce_sum(float v) {
    #pragma unroll
    for (int o = 32; o > 0; o >>= 1) v += __shfl_xor(v, o, 64);
    return v;
}
// Sum when only lanes == 0 (mod G) hold nonzero values.
template<int G>
__device__ __forceinline__ float reduce_leaders(float v) {
    #pragma unroll
    for (int o = G; o < 64; o <<= 1) v += __shfl_xor(v, o, 64);
    return v;  // lane 0 holds the wave total
}

// R/S for one segment; P4[e] = P[4e], prefix of squared adjacent diffs.
// FLO = b&3, FHI = (b+W-1)&3, both compile-time at every call site.
template<int FLO, int FHI>
__device__ __forceinline__ float seg_rs2(const float* __restrict__ row,
                                         const float* __restrict__ P4,
                                         int b, int W, float m, float invwm2,
                                         float mx, float mn) {
    float plo = P4[b >> 2];
    if constexpr (FLO > 0) {
        const int k0 = b - FLO;  // = b & ~3
        #pragma unroll
        for (int t = 0; t < FLO; ++t) {
            float d = row[k0 + t + 1] - row[k0 + t];
            plo = fmaf(d, d, plo);
        }
    }
    const int e = b + W - 1;
    float phi = P4[e >> 2];
    if constexpr (FHI > 0) {
        const int k0 = e - FHI;  // = e & ~3
        #pragma unroll
        for (int t = 0; t < FHI; ++t) {
            float d = row[k0 + t + 1] - row[k0 + t];
            phi = fmaf(d, d, phi);
        }
    }
    float ss  = phi - plo;
    float var = fmaf(-(float)(W - 1) * m, m, ss) * invwm2;
    float S   = __builtin_amdgcn_sqrtf(fmaxf(var, 0.0f));
    return (mx - mn) * __builtin_amdgcn_rcpf(S + EPSF);
}

// Fold slots LO..HI of chunk q (j of slot r = JB + r, compile-time) into mx/mn.
template<int LO, int HI, int JB>
__device__ __forceinline__ void chunk_fold(const float4 q, float nm, float& mx, float& mn) {
    if constexpr (LO <= HI) {
        constexpr int NV = HI - LO + 1;
        float v[NV];
        #pragma unroll
        for (int r = 0; r < NV; ++r)
            v[r] = fmaf((float)(JB + LO + r), nm, (&q.x)[LO + r]);
        if constexpr (NV == 1) { mx = fmaxf(mx, v[0]); mn = fminf(mn, v[0]); }
        else if constexpr (NV == 2) { mx = max3f(mx, v[0], v[1]); mn = min3f(mn, v[0], v[1]); }
        else if constexpr (NV == 3) { mx = fmaxf(mx, max3f(v[0], v[1], v[2]));
                                      mn = fminf(mn, min3f(v[0], v[1], v[2])); }
        else { mx = max3f(max3f(mx, v[0], v[1]), v[2], v[3]);
               mn = min3f(min3f(mn, v[0], v[1]), v[2], v[3]); }
    }
}

// ---- W=10 hand path: pair task (2 segs, 5 preloaded chunks, all-register) ----
__device__ __forceinline__ float w10_task(const float* __restrict__ row,
                                          const float* __restrict__ P4,
                                          int t, bool pair) {
    const int b = t * 20;
    const int h = t * 5;              // P4 base index = b/4
    const float4* p = (const float4*)(row + b);
    float4 q0 = p[0], q1 = p[1], q2 = p[2];
    float acc;
    {
        const float m = (q2.y - q0.x) * (1.0f / 9.0f), nm = -m;
        float v1 = fmaf(1.0f, nm, q0.y);
        float v2 = fmaf(2.0f, nm, q0.z);
        float v3 = fmaf(3.0f, nm, q0.w);
        float mx = max3f(v1, v2, v3), mn = min3f(v1, v2, v3);
        float v4 = fmaf(4.0f, nm, q1.x);
        float v5 = fmaf(5.0f, nm, q1.y);
        float v6 = fmaf(6.0f, nm, q1.z);
        float v7 = fmaf(7.0f, nm, q1.w);
        mx = max3f(mx, v4, v5); mn = min3f(mn, v4, v5);
        mx = max3f(mx, v6, v7); mn = min3f(mn, v6, v7);
        float v8 = fmaf(8.0f, nm, q2.x);
        float v9 = fmaf(9.0f, nm, q2.y);
        mx = max3f(mx, v8, v9); mn = min3f(mn, v8, v9);
        float d8 = q2.y - q2.x;                     // d at k=b+8
        float ss = fmaf(d8, d8, P4[h + 2]) - P4[h]; // P[b+9] - P[b]
        float var = fmaf(-9.0f * m, m, ss) * 0.125f;
        float S = __builtin_amdgcn_sqrtf(fmaxf(var, 0.0f));
        acc = (mx - mn) * __builtin_amdgcn_rcpf(S + EPSF);
    }
    if (pair) {
        float4 q3 = p[3], q4 = p[4];
        const float m = (q4.w - q2.z) * (1.0f / 9.0f), nm = -m;
        float v1 = fmaf(1.0f, nm, q2.w);
        float v2 = fmaf(2.0f, nm, q3.x);
        float v3 = fmaf(3.0f, nm, q3.y);
        float mx = max3f(v1, v2, v3), mn = min3f(v1, v2, v3);
        float v4 = fmaf(4.0f, nm, q3.z);
        float v5 = fmaf(5.0f, nm, q3.w);
        float v6 = fmaf(6.0f, nm, q4.x);
        float v7 = fmaf(7.0f, nm, q4.y);
        mx = max3f(mx, v4, v5); mn = min3f(mn, v4, v5);
        mx = max3f(mx, v6, v7); mn = min3f(mn, v6, v7);
        float v8 = fmaf(8.0f, nm, q4.z);
        float v9 = fmaf(9.0f, nm, q4.w);
        mx = max3f(mx, v8, v9); mn = min3f(mn, v8, v9);
        // P[b+10] = P4[h+2] + d8^2 + d9^2 ; P[b+19] = P4[h+4] + d16^2+d17^2+d18^2
        float d8  = q2.y - q2.x;
        float d9  = q2.z - q2.y;
        float d16 = q4.y - q4.x;
        float d17 = q4.z - q4.y;
        float d18 = q4.w - q4.z;
        float plo = fmaf(d9, d9, fmaf(d8, d8, P4[h + 2]));
        float phi = fmaf(d18, d18, fmaf(d17, d17, fmaf(d16, d16, P4[h + 4])));
        float ss = phi - plo;
        float var = fmaf(-9.0f * m, m, ss) * 0.125f;
        float S = __builtin_amdgcn_sqrtf(fmaxf(var, 0.0f));
        acc += (mx - mn) * __builtin_amdgcn_rcpf(S + EPSF);
    }
    return acc;
}

// ---- Multi-segment aligned tasks (odd W, base 16B-aligned) ----
template<int W, int NSEG, int C>
__device__ __forceinline__ void mchunk_step(const float4* __restrict__ p,
                                            const float (&nm)[NSEG],
                                            float (&mx)[NSEG], float (&mn)[NSEG]) {
    constexpr int E0 = 4 * C;
    constexpr int K0 = E0 / W;
    constexpr int SA = K0 * W;
    constexpr int LOA = (SA == E0) ? 1 : 0;
    constexpr int HIA_ = SA + W - 1 - E0;
    constexpr int HIA = HIA_ < 3 ? HIA_ : 3;
    float4 q = p[C];
    if constexpr (K0 < NSEG)
        chunk_fold<LOA, HIA, E0 - SA>(q, nm[K0], mx[K0], mn[K0]);
    constexpr bool HASB = (K0 + 1 < NSEG) && (SA + W + 1 - E0 <= 3);
    if constexpr (HASB) {
        constexpr int SB = SA + W;
        chunk_fold<SB + 1 - E0, 3, E0 - SB>(q, nm[K0 + 1], mx[K0 + 1], mn[K0 + 1]);
    }
}

template<int W, int NSEG, int... Cs>
__device__ __forceinline__ void mseg_all(const float4* __restrict__ p,
                                         const float (&nm)[NSEG],
                                         float (&mx)[NSEG], float (&mn)[NSEG],
                                         std::integer_sequence<int, Cs...>) {
    (mchunk_step<W, NSEG, Cs>(p, nm, mx, mn), ...);
}

template<int W, int NSEG, int... Ks>
__device__ __forceinline__ float mseg_rs_all(const float* __restrict__ row,
                                             const float* __restrict__ P4, int b,
                                             const float (&m)[NSEG],
                                             const float (&mx)[NSEG], const float (&mn)[NSEG],
                                             std::integer_sequence<int, Ks...>) {
    constexpr float invwm2 = 1.0f / (float)(W - 2);
    float acc = 0.0f;
    ((acc += seg_rs2<(W * Ks) & 3, (W * Ks + W - 1) & 3>(
          row, P4, b + Ks * W, W, m[Ks], invwm2, mx[Ks], mn[Ks])), ...);
    return acc;
}

// Odd W, b divisible by 4 -> per-seg prefix residues are compile-time.
template<int W, int NSEG>
__device__ __forceinline__ float mseg_task_odd(const float* __restrict__ row,
                                               const float* __restrict__ P4, int b) {
    constexpr int NCH = (W * NSEG + 3) / 4;
    const float4* p = (const float4*)(row + b);
    float nm[NSEG], m[NSEG], mx[NSEG], mn[NSEG];
    #pragma unroll
    for (int k = 0; k < NSEG; ++k) {
        float a0 = row[b + k * W];
        float a1 = row[b + k * W + W - 1];
        m[k] = (a1 - a0) * (1.0f / (float)(W - 1));
        nm[k] = -m[k];
        mx[k] = -INFINITY; mn[k] = INFINITY;
    }
    mseg_all<W, NSEG>(p, nm, mx, mn, std::make_integer_sequence<int, NCH>{});
    return mseg_rs_all<W, NSEG>(row, P4, b, m, mx, mn,
                                std::make_integer_sequence<int, NSEG>{});
}

// ---- Packed strided single-segment bulk with batched loads ----
template<int W, int A, int G>
__device__ __forceinline__ void seg_strided_pk(const float* __restrict__ row, int b, int lane,
                                               float nm, float& mx, float& mn) {
    constexpr int NCH  = (A + W - 1) / 4 + 1;
    constexpr int HIL  = (A + W - 1) & 3;
    constexpr int MAIN_END = (HIL == 3) ? NCH : NCH - 1;
    constexpr int NFULL = MAIN_END - 1;           // full chunks are 1..NFULL
    constexpr int FULL  = NFULL / G;
    constexpr int REM   = NFULL % G;
    constexpr int NB    = FULL + (REM > 0 ? 1 : 0);
    const float4* p  = (const float4*)(row + (b - A));
    const float4* pl = p + (1 + lane);
    // Batch all loads first: back-to-back ds_read_b128, counted waits.
    float4 qs[NB > 0 ? NB : 1];
    #pragma unroll
    for (int i = 0; i < FULL; ++i) qs[i] = pl[i * G];
    if constexpr (REM > 0) { if (lane < REM) qs[FULL] = pl[FULL * G]; }
    mx = -INFINITY; mn = INFINITY;
    v2f jc; jc.x = (float)(4 * (1 + lane) - A); jc.y = jc.x + 1.0f;
    const v2f nm2   = {nm, nm};
    const v2f nm2x2 = {nm + nm, nm + nm};
    const v2f step  = {(float)(4 * G), (float)(4 * G)};
    #pragma unroll
    for (int i = 0; i < FULL; ++i) {
        float4 q = qs[i];
        v2f q01 = {q.x, q.y}, q23 = {q.z, q.w};
        v2f t01 = pk_fma(jc, nm2, q01);
        v2f t23 = pk_fma(jc, nm2, pk_add(q23, nm2x2));
        mx = max3f(max3f(mx, t01.x, t01.y), t23.x, t23.y);
        mn = min3f(min3f(mn, t01.x, t01.y), t23.x, t23.y);
        jc = pk_add(jc, step);
    }
    if constexpr (REM > 0) {
        if (lane < REM) {
            float4 q = qs[FULL];
            v2f q01 = {q.x, q.y}, q23 = {q.z, q.w};
            v2f t01 = pk_fma(jc, nm2, q01);
            v2f t23 = pk_fma(jc, nm2, pk_add(q23, nm2x2));
            mx = max3f(max3f(mx, t01.x, t01.y), t23.x, t23.y);
            mn = min3f(min3f(mn, t01.x, t01.y), t23.x, t23.y);
        }
    }
    if constexpr (A < 3) {
        if (lane == 0) chunk_fold<A + 1, 3, -A>(p[0], nm, mx, mn);
    }
    if constexpr (HIL != 3) {
        if (lane == 1) chunk_fold<0, HIL, 4 * (NCH - 1) - A>(p[NCH - 1], nm, mx, mn);
    }
}

// Group of G lanes -> one segment; rs contribution on lane 0 of the group.
template<int W, int A, int G>
__device__ __forceinline__ float group_seg(const float* __restrict__ row,
                                           const float* __restrict__ P4,
                                           int s, int lane) {
    const int b = s * W;
    float a0 = row[b], a1 = row[b + W - 1];
    float m = (a1 - a0) * (1.0f / (float)(W - 1));
    float nm = -m;
    float mx, mn;
    seg_strided_pk<W, A, G>(row, b, lane, nm, mx, mn);
    #pragma unroll
    for (int o = G / 2; o > 0; o >>= 1) {
        mx = fmaxf(mx, __shfl_xor(mx, o, G));
        mn = fminf(mn, __shfl_xor(mn, o, G));
    }
    float r = seg_rs2<A, (A + W - 1) & 3>(
        row, P4, b, W, m, 1.0f / (float)(W - 2), mx, mn);
    return (lane == 0) ? r : 0.0f;
}

__global__ __launch_bounds__(BLOCK, 7) void hurst_kernel(const float* __restrict__ x,
                                                         float* __restrict__ out) {
    __shared__ __align__(16) float row[TLEN];
    __shared__ __align__(16) float P4[TLEN / 4];
    __shared__ float rs_sum[NW];
    __shared__ float wred[8];

    const int tid = threadIdx.x;
    const int r = blockIdx.x;
    const int w = tid >> 6, l = tid & 63;

    // One coalesced HBM pass per row.
    const float4* src = (const float4*)(x + (size_t)r * TLEN);
    float4* dst = (float4*)row;
    #pragma unroll
    for (int i = 0; i < TLEN / 4 / BLOCK; ++i)
        dst[tid + i * BLOCK] = src[tid + i * BLOCK];
    if (tid < NW) rs_sum[tid] = 0.0f;
    __syncthreads();

    // ---- Build P4: prefix sums of squared adjacent diffs at indices %4==0 ----
    {
        const int base = tid * 16;
        float v[17];
        const float4* rp = (const float4*)(row + base);
        float4 q0 = rp[0], q1 = rp[1], q2 = rp[2], q3 = rp[3];
        v[0]=q0.x;  v[1]=q0.y;  v[2]=q0.z;  v[3]=q0.w;
        v[4]=q1.x;  v[5]=q1.y;  v[6]=q1.z;  v[7]=q1.w;
        v[8]=q2.x;  v[9]=q2.y;  v[10]=q2.z; v[11]=q2.w;
        v[12]=q3.x; v[13]=q3.y; v[14]=q3.z; v[15]=q3.w;
        v[16] = row[(base + 16 < TLEN) ? base + 16 : TLEN - 1];

        float pl4[4];
        float c = 0.0f;
        #pragma unroll
        for (int j = 0; j < 16; ++j) {
            if ((j & 3) == 0) pl4[j >> 2] = c;
            float d = v[j + 1] - v[j];
            c = fmaf(d, d, c);
        }
        const float total = c;
        float incl = total;
        #pragma unroll
        for (int o = 1; o < 64; o <<= 1) {
            float u = __shfl_up(incl, o, 64);
            if (l >= o) incl += u;
        }
        if (l == 63) wred[w] = incl;
        __syncthreads();
        float off = incl - total;
        #pragma unroll
        for (int w2 = 0; w2 < 4; ++w2)
            if (w2 < w) off += wred[w2];
        float4* pp = (float4*)(P4 + tid * 4);
        pp[0] = make_float4(off + pl4[0], off + pl4[1], off + pl4[2], off + pl4[3]);
    }
    __syncthreads();

    // ================= wave phase (no __syncthreads inside) =================

    // W=10 (idx 0): 204 pair-tasks + 1 solo, register-resident, all waves.
    {
        float a = 0.0f;
        if (tid < 204)       a = w10_task(row, P4, tid, true);
        else if (tid == 204) a = w10_task(row, P4, 204, false);
        a = wave_reduce_sum(a);
        if (l == 0) atomicAdd(&rs_sum[0], a);
    }
    // W=17 (idx 1) wave 0; W=31 (idx 2) wave 1 (concurrent).
    if (w == 0) {
        float a = (l < 60) ? mseg_task_odd<17, 4>(row, P4, l * 68) : 0.0f;
        a = wave_reduce_sum(a);
        if (l == 0) atomicAdd(&rs_sum[1], a);
    } else if (w == 1) {
        float a = (l < 33) ? mseg_task_odd<31, 4>(row, P4, l * 124) : 0.0f;
        a = wave_reduce_sum(a);
        if (l == 0) atomicAdd(&rs_sum[2], a);
    }
    // W=56 (idx 3): pass1 all waves (segs 0..63); pass2 wave 2 (segs 64..72).
    {
        const int g = tid >> 2, gl = tid & 3;
        float a = group_seg<56, 0, 4>(row, P4, g, gl);
        if (w == 2) {
            int s2 = 64 + ((tid - 128) >> 2);
            if (s2 < 73) a += group_seg<56, 0, 4>(row, P4, s2, gl);
        }
        a = reduce_leaders<4>(a);
        if (l == 0) atomicAdd(&rs_sum[3], a);
    }
    // W=100 (idx 4): pass1 all waves (segs 0..31); pass2 wave 3 (segs 32..39).
    {
        const int g = tid >> 3, gl = tid & 7;
        float a = group_seg<100, 0, 8>(row, P4, g, gl);
        if (w == 3)
            a += group_seg<100, 0, 8>(row, P4, 32 + ((tid - 192) >> 3), gl);
        a = reduce_leaders<8>(a);
        if (l == 0) atomicAdd(&rs_sum[4], a);
    }
    // W=177 (idx 5): G=16; alignment class A = s&3 mapped per wave (balanced).
    {
        const int g4 = (tid >> 4) & 3, gl16 = tid & 15;
        float a = 0.0f;
        if (w == 0) {
            a = group_seg<177, 0, 16>(row, P4, 4 * g4, gl16);
            if (g4 < 2) a += group_seg<177, 0, 16>(row, P4, 4 * (g4 + 4), gl16);
        } else if (w == 1) {
            a = group_seg<177, 1, 16>(row, P4, 4 * g4 + 1, gl16);
            if (g4 < 2) a += group_seg<177, 1, 16>(row, P4, 4 * (g4 + 4) + 1, gl16);
        } else if (w == 2) {
            a = group_seg<177, 2, 16>(row, P4, 4 * g4 + 2, gl16);
            if (g4 < 2) a += group_seg<177, 2, 16>(row, P4, 4 * (g4 + 4) + 2, gl16);
        } else {
            a = group_seg<177, 3, 16>(row, P4, 4 * g4 + 3, gl16);
            if (g4 < 1) a += group_seg<177, 3, 16>(row, P4, 4 * (g4 + 4) + 3, gl16);
        }
        a = reduce_leaders<16>(a);
        if (l == 0) atomicAdd(&rs_sum[5], a);
    }
    // W=316 (idx 6): G=16, 12 segs on waves {0,2,3} (wave1 carries W=31).
    if (w != 1) {
        const int g4 = (tid >> 4) & 3, gl16 = tid & 15;
        const int base = (w == 0) ? 0 : (w == 2) ? 4 : 8;
        float a = group_seg<316, 0, 16>(row, P4, base + g4, gl16);
        a = reduce_leaders<16>(a);
        if (l == 0) atomicAdd(&rs_sum[6], a);
    }
    // W=562 (idx 7): 7 segs; even s (A=0) on wave 2, odd s (A=2) on wave 3.
    {
        const int gh = (tid >> 5) & 1, gl32 = tid & 31;
        if (w == 2) {
            float a = group_seg<562, 0, 32>(row, P4, 2 * gh, gl32);
            a += group_seg<562, 0, 32>(row, P4, 4 + 2 * gh, gl32);
            a = reduce_leaders<32>(a);
            if (l == 0) atomicAdd(&rs_sum[7], a);
        } else if (w == 3) {
            float a = group_seg<562, 2, 32>(row, P4, 1 + 2 * gh, gl32);
            if (gh == 0) a += group_seg<562, 2, 32>(row, P4, 5, gl32);
            a = reduce_leaders<32>(a);
            if (l == 0) atomicAdd(&rs_sum[7], a);
        }
    }
    // W=1000 (idx 8): 4 segs, G=32: wave2 segs {0,1}, wave3 segs {2,3}.
    if (w >= 2) {
        const int gh = (tid >> 5) & 1, gl32 = tid & 31;
        const int s = (w == 2 ? 0 : 2) + gh;
        float a = group_seg<1000, 0, 32>(row, P4, s, gl32);
        a = reduce_leaders<32>(a);
        if (l == 0) atomicAdd(&rs_sum[8], a);
    }

    // ================= block phase =================

    // W=1778 (idx 9): waves {0,1} -> seg0 (A=0), waves {2,3} -> seg1 (A=2).
    {
        const int half = tid >> 7, hl = tid & 127;
        const int b = half ? 1778 : 0;
        float m = (row[b + 1777] - row[b]) * (1.0f / 1777.0f);
        float nm = -m, mx, mn;
        if (half == 0) seg_strided_pk<1778, 0, 128>(row, 0,    hl, nm, mx, mn);
        else           seg_strided_pk<1778, 2, 128>(row, 1778, hl, nm, mx, mn);
        #pragma unroll
        for (int o = 32; o > 0; o >>= 1) {
            mx = fmaxf(mx, __shfl_xor(mx, o, 64));
            mn = fminf(mn, __shfl_xor(mn, o, 64));
        }
        if (l == 0) { wred[w * 2] = mx; wred[w * 2 + 1] = mn; }
        __syncthreads();
        if ((tid & 127) == 0) {
            const int wb = tid >> 6;  // 0 or 2
            float MX = fmaxf(wred[wb * 2],     wred[wb * 2 + 2]);
            float MN = fminf(wred[wb * 2 + 1], wred[wb * 2 + 3]);
            float v;
            if (tid == 0) v = seg_rs2<0, 1>(row, P4, 0,    1778, m, 1.0f / 1776.0f, MX, MN);
            else          v = seg_rs2<2, 3>(row, P4, 1778, 1778, m, 1.0f / 1776.0f, MX, MN);
            atomicAdd(&rs_sum[9], v);
        }
        __syncthreads();
    }
    // W=3162 (idx 10): whole block, 1 segment.
    {
        float m = (row[3161] - row[0]) * (1.0f / 3161.0f);
        float nm = -m, mx, mn;
        seg_strided_pk<3162, 0, 256>(row, 0, tid, nm, mx, mn);
        #pragma unroll
        for (int o = 32; o > 0; o >>= 1) {
            mx = fmaxf(mx, __shfl_xor(mx, o, 64));
            mn = fminf(mn, __shfl_xor(mn, o, 64));
        }
        if (l == 0) { wred[w * 2] = mx; wred[w * 2 + 1] = mn; }
        __syncthreads();
        if (tid == 0) {
            float MX = fmaxf(fmaxf(wred[0], wred[2]), fmaxf(wred[4], wred[6]));
            float MN = fminf(fminf(wred[1], wred[3]), fminf(wred[5], wred[7]));
            atomicAdd(&rs_sum[10],
                      seg_rs2<0, 1>(row, P4, 0, 3162, m, 1.0f / 3160.0f, MX, MN));
        }
        __syncthreads();
    }
    // W=4096 (idx 11): whole block, 1 segment.
    {
        float m = (row[4095] - row[0]) * (1.0f / 4095.0f);
        float nm = -m, mx, mn;
        seg_strided_pk<4096, 0, 256>(row, 0, tid, nm, mx, mn);
        #pragma unroll
        for (int o = 32; o > 0; o >>= 1) {
            mx = fmaxf(mx, __shfl_xor(mx, o, 64));
            mn = fminf(mn, __shfl_xor(mn, o, 64));
        }
        if (l == 0) { wred[w * 2] = mx; wred[w * 2 + 1] = mn; }
        __syncthreads();
        if (tid == 0) {
            float MX = fmaxf(fmaxf(wred[0], wred[2]), fmaxf(wred[4], wred[6]));
            float MN = fminf(fminf(wred[1], wred[3]), fminf(wred[5], wred[7]));
            atomicAdd(&rs_sum[11],
                      seg_rs2<0, 3>(row, P4, 0, 4096, m, 1.0f / 4094.0f, MX, MN));
        }
        __syncthreads();
    }

    // ================= epilogue =================
    if (tid < 64) {
        float t = 0.0f;
        if (tid < NW) {
            float rs = fmaf(rs_sum[tid], INVN_TAB[tid], EPSF);
            t = __builtin_amdgcn_logf(rs) * (LOG10_2) * XC_TAB[tid];
        }
        t = wave_reduce_sum(t);
        if (tid == 0) {
            float h = t * INV_DEN;
            if (!isfinite(h)) h = 1.0f;
            out[r] = h;
        }
    }
}

extern "C" void kernel_launch(void* const* d_in, const int* in_sizes, int n_in,
                              void* d_out, int out_size, void* d_ws, size_t ws_size,
                              hipStream_t stream) {
    const float* x = (const float*)d_in[0];
    float* out = (float*)d_out;
    const int B = out_size;  // 8192 rows
    hipLaunchKernelGGL(hurst_kernel, dim3(B), dim3(BLOCK), 0, stream, x, out);
}

// Round 6
// 87.290 us; speedup vs baseline: 2.2532x; 1.0317x over previous
//
#include <hip/hip_runtime.h>
#include <math.h>
#include <utility>

#define TLEN 4096
#define NW   12
#define BLOCK 256
#define EPSF 1e-6f

typedef float v2f __attribute__((ext_vector_type(2)));

// Centered log10(w+1e-6) values (sum = 0) and 1/n_segments, precomputed in double.
__device__ const float XC_TAB[NW] = {
    -1.3608041f, -1.1303552f, -0.8694424f, -0.6126161f,
    -0.3608041f, -0.1128308f,  0.1388830f,  0.3889322f,
     0.6391959f,  0.8891277f,  1.1391578f,  1.2515558f };
__device__ const float INVN_TAB[NW] = {
    1.0f/409.0f, 1.0f/240.0f, 1.0f/132.0f, 1.0f/73.0f,
    1.0f/40.0f,  1.0f/23.0f,  1.0f/12.0f,  1.0f/7.0f,
    0.25f, 0.5f, 1.0f, 1.0f };
#define INV_DEN 0.11577579f
#define LOG10_2 0.30102999566f

__device__ __forceinline__ float max3f(float a, float b, float c) {
    float r; asm("v_max3_f32 %0, %1, %2, %3" : "=v"(r) : "v"(a), "v"(b), "v"(c)); return r;
}
__device__ __forceinline__ float min3f(float a, float b, float c) {
    float r; asm("v_min3_f32 %0, %1, %2, %3" : "=v"(r) : "v"(a), "v"(b), "v"(c)); return r;
}
__device__ __forceinline__ v2f pk_fma(v2f a, v2f b, v2f c) {
    v2f d; asm("v_pk_fma_f32 %0, %1, %2, %3" : "=v"(d) : "v"(a), "v"(b), "v"(c)); return d;
}
__device__ __forceinline__ v2f pk_add(v2f a, v2f b) {
    v2f d; asm("v_pk_add_f32 %0, %1, %2" : "=v"(d) : "v"(a), "v"(b)); return d;
}

__device__ __forceinline__ float wave_reduce_sum(float v) {
    #pragma unroll
    for (int o = 32; o > 0; o >>= 1) v += __shfl_xor(v, o, 64);
    return v;
}
template<int G>
__device__ __forceinline__ float reduce_leaders(float v) {
    #pragma unroll
    for (int o = G; o < 64; o <<= 1) v += __shfl_xor(v, o, 64);
    return v;
}

// R/S for one segment; P4[e] = P[4e], prefix of squared adjacent diffs.
// FLO = b&3, FHI = (b+W-1)&3, both compile-time at every call site.
template<int FLO, int FHI>
__device__ __forceinline__ float seg_rs2(const float* __restrict__ row,
                                         const float* __restrict__ P4,
                                         int b, int W, float m, float invwm2,
                                         float mx, float mn) {
    float plo = P4[b >> 2];
    if constexpr (FLO > 0) {
        const int k0 = b - FLO;
        #pragma unroll
        for (int t = 0; t < FLO; ++t) {
            float d = row[k0 + t + 1] - row[k0 + t];
            plo = fmaf(d, d, plo);
        }
    }
    const int e = b + W - 1;
    float phi = P4[e >> 2];
    if constexpr (FHI > 0) {
        const int k0 = e - FHI;
        #pragma unroll
        for (int t = 0; t < FHI; ++t) {
            float d = row[k0 + t + 1] - row[k0 + t];
            phi = fmaf(d, d, phi);
        }
    }
    float ss  = phi - plo;
    float var = fmaf(-(float)(W - 1) * m, m, ss) * invwm2;
    float S   = __builtin_amdgcn_sqrtf(fmaxf(var, 0.0f));
    return (mx - mn) * __builtin_amdgcn_rcpf(S + EPSF);
}

// Fold slots LO..HI of chunk q (j of slot s = JB + s, compile-time) into mx/mn.
template<int LO, int HI, int JB>
__device__ __forceinline__ void chunk_fold(const float4 q, float nm, float& mx, float& mn) {
    if constexpr (LO <= HI) {
        constexpr int NV = HI - LO + 1;
        float v[NV];
        #pragma unroll
        for (int r = 0; r < NV; ++r)
            v[r] = fmaf((float)(JB + LO + r), nm, (&q.x)[LO + r]);
        if constexpr (NV == 1) { mx = fmaxf(mx, v[0]); mn = fminf(mn, v[0]); }
        else if constexpr (NV == 2) { mx = max3f(mx, v[0], v[1]); mn = min3f(mn, v[0], v[1]); }
        else if constexpr (NV == 3) { mx = fmaxf(mx, max3f(v[0], v[1], v[2]));
                                      mn = fminf(mn, min3f(v[0], v[1], v[2])); }
        else { mx = max3f(max3f(mx, v[0], v[1]), v[2], v[3]);
               mn = min3f(min3f(mn, v[0], v[1]), v[2], v[3]); }
    }
}

// ---- Multi-segment tasks with base parity BP (true base b, b&3 == BP) ----
// Chunk pointer p = row + b - BP; element t of slot s in chunk C: t = 4C + s - BP.
template<int W, int NSEG, int BP, int C>
__device__ __forceinline__ void mchunk_stepA(const float4* __restrict__ p,
                                             const float (&nm)[NSEG],
                                             float (&mx)[NSEG], float (&mn)[NSEG]) {
    float4 q = p[C];
    if constexpr (C == 0 && BP > 0) {
        // slots BP..3 -> t = 0..3-BP; skip t==0 (j=0)
        chunk_fold<BP + 1, 3, -BP>(q, nm[0], mx[0], mn[0]);
    } else {
        constexpr int E0 = 4 * C - BP;   // >= 0 here
        constexpr int K0 = E0 / W;
        constexpr int SA = K0 * W;
        constexpr int LOA = (SA == E0) ? 1 : 0;
        constexpr int HIA1 = SA + W - 1 - E0;
        constexpr int HIA2 = NSEG * W - 1 - E0;
        constexpr int HIA = (3 < HIA1 ? (3 < HIA2 ? 3 : HIA2) : (HIA1 < HIA2 ? HIA1 : HIA2));
        if constexpr (K0 < NSEG)
            chunk_fold<LOA, HIA, E0 - SA>(q, nm[K0], mx[K0], mn[K0]);
        constexpr int SB = SA + W;
        constexpr bool HASB = (K0 + 1 < NSEG) && (SB + 1 - E0 <= 3);
        if constexpr (HASB) {
            constexpr int HIB2 = NSEG * W - 1 - E0;
            constexpr int HIB = (3 < HIB2 ? 3 : HIB2);
            chunk_fold<SB + 1 - E0, HIB, E0 - SB>(q, nm[K0 + 1], mx[K0 + 1], mn[K0 + 1]);
        }
    }
}

template<int W, int NSEG, int BP, int... Cs>
__device__ __forceinline__ void mseg_allA(const float4* __restrict__ p,
                                          const float (&nm)[NSEG],
                                          float (&mx)[NSEG], float (&mn)[NSEG],
                                          std::integer_sequence<int, Cs...>) {
    (mchunk_stepA<W, NSEG, BP, Cs>(p, nm, mx, mn), ...);
}

template<int W, int NSEG, int BP, int... Ks>
__device__ __forceinline__ float mseg_rs_allA(const float* __restrict__ row,
                                              const float* __restrict__ P4, int b,
                                              const float (&m)[NSEG],
                                              const float (&mx)[NSEG], const float (&mn)[NSEG],
                                              std::integer_sequence<int, Ks...>) {
    constexpr float invwm2 = 1.0f / (float)(W - 2);
    float acc = 0.0f;
    ((acc += seg_rs2<(BP + W * Ks) & 3, (BP + W * Ks + W - 1) & 3>(
          row, P4, b + Ks * W, W, m[Ks], invwm2, mx[Ks], mn[Ks])), ...);
    return acc;
}

template<int W, int NSEG, int BP>
__device__ __forceinline__ float mseg_task_a(const float* __restrict__ row,
                                             const float* __restrict__ P4, int b) {
    constexpr int NCH = (BP + W * NSEG + 3) / 4;
    const float4* p = (const float4*)(row + b - BP);
    float nm[NSEG], m[NSEG], mx[NSEG], mn[NSEG];
    #pragma unroll
    for (int k = 0; k < NSEG; ++k) {
        float a0 = row[b + k * W];
        float a1 = row[b + k * W + W - 1];
        m[k] = (a1 - a0) * (1.0f / (float)(W - 1));
        nm[k] = -m[k];
        mx[k] = -INFINITY; mn[k] = INFINITY;
    }
    mseg_allA<W, NSEG, BP>(p, nm, mx, mn, std::make_integer_sequence<int, NCH>{});
    return mseg_rs_allA<W, NSEG, BP>(row, P4, b, m, mx, mn,
                                     std::make_integer_sequence<int, NSEG>{});
}

// ---- Packed strided single-segment bulk with batched loads ----
template<int W, int A, int G>
__device__ __forceinline__ void seg_strided_pk(const float* __restrict__ row, int b, int lane,
                                               float nm, float& mx, float& mn) {
    constexpr int NCH  = (A + W - 1) / 4 + 1;
    constexpr int HIL  = (A + W - 1) & 3;
    constexpr int MAIN_END = (HIL == 3) ? NCH : NCH - 1;
    constexpr int NFULL = MAIN_END - 1;
    constexpr int FULL  = NFULL / G;
    constexpr int REM   = NFULL % G;
    constexpr int NB    = FULL + (REM > 0 ? 1 : 0);
    const float4* p  = (const float4*)(row + (b - A));
    const float4* pl = p + (1 + lane);
    float4 qs[NB > 0 ? NB : 1];
    #pragma unroll
    for (int i = 0; i < FULL; ++i) qs[i] = pl[i * G];
    if constexpr (REM > 0) { if (lane < REM) qs[FULL] = pl[FULL * G]; }
    mx = -INFINITY; mn = INFINITY;
    v2f jc; jc.x = (float)(4 * (1 + lane) - A); jc.y = jc.x + 1.0f;
    const v2f nm2   = {nm, nm};
    const v2f nm2x2 = {nm + nm, nm + nm};
    const v2f step  = {(float)(4 * G), (float)(4 * G)};
    #pragma unroll
    for (int i = 0; i < FULL; ++i) {
        float4 q = qs[i];
        v2f q01 = {q.x, q.y}, q23 = {q.z, q.w};
        v2f t01 = pk_fma(jc, nm2, q01);
        v2f t23 = pk_fma(jc, nm2, pk_add(q23, nm2x2));
        mx = max3f(max3f(mx, t01.x, t01.y), t23.x, t23.y);
        mn = min3f(min3f(mn, t01.x, t01.y), t23.x, t23.y);
        jc = pk_add(jc, step);
    }
    if constexpr (REM > 0) {
        if (lane < REM) {
            float4 q = qs[FULL];
            v2f q01 = {q.x, q.y}, q23 = {q.z, q.w};
            v2f t01 = pk_fma(jc, nm2, q01);
            v2f t23 = pk_fma(jc, nm2, pk_add(q23, nm2x2));
            mx = max3f(max3f(mx, t01.x, t01.y), t23.x, t23.y);
            mn = min3f(min3f(mn, t01.x, t01.y), t23.x, t23.y);
        }
    }
    if constexpr (A < 3) {
        if (lane == 0) chunk_fold<A + 1, 3, -A>(p[0], nm, mx, mn);
    }
    if constexpr (HIL != 3) {
        if (lane == 1) chunk_fold<0, HIL, 4 * (NCH - 1) - A>(p[NCH - 1], nm, mx, mn);
    }
}

template<int W, int A, int G>
__device__ __forceinline__ float group_seg(const float* __restrict__ row,
                                           const float* __restrict__ P4,
                                           int s, int lane) {
    const int b = s * W;
    float a0 = row[b], a1 = row[b + W - 1];
    float m = (a1 - a0) * (1.0f / (float)(W - 1));
    float nm = -m;
    float mx, mn;
    seg_strided_pk<W, A, G>(row, b, lane, nm, mx, mn);
    #pragma unroll
    for (int o = G / 2; o > 0; o >>= 1) {
        mx = fmaxf(mx, __shfl_xor(mx, o, G));
        mn = fminf(mn, __shfl_xor(mn, o, G));
    }
    float r = seg_rs2<A, (A + W - 1) & 3>(
        row, P4, b, W, m, 1.0f / (float)(W - 2), mx, mn);
    return (lane == 0) ? r : 0.0f;
}

// One W=10 segment from registers v[B..B+9]; ss = sum of its 9 squared diffs.
template<int B, int NV>
__device__ __forceinline__ float w10_seg(const float (&v)[NV], float ss) {
    const float m = (v[B + 9] - v[B]) * (1.0f / 9.0f), nm = -m;
    float x1 = fmaf(1.0f, nm, v[B + 1]);
    float x2 = fmaf(2.0f, nm, v[B + 2]);
    float x3 = fmaf(3.0f, nm, v[B + 3]);
    float x4 = fmaf(4.0f, nm, v[B + 4]);
    float x5 = fmaf(5.0f, nm, v[B + 5]);
    float x6 = fmaf(6.0f, nm, v[B + 6]);
    float x7 = fmaf(7.0f, nm, v[B + 7]);
    float x8 = fmaf(8.0f, nm, v[B + 8]);
    float x9 = fmaf(9.0f, nm, v[B + 9]);
    float mx = max3f(x1, x2, x3);
    mx = max3f(mx, x4, x5); mx = max3f(mx, x6, x7); mx = max3f(mx, x8, x9);
    float mn = min3f(x1, x2, x3);
    mn = min3f(mn, x4, x5); mn = min3f(mn, x6, x7); mn = min3f(mn, x8, x9);
    float var = fmaf(-9.0f * m, m, ss) * 0.125f;
    float S = __builtin_amdgcn_sqrtf(fmaxf(var, 0.0f));
    return (mx - mn) * __builtin_amdgcn_rcpf(S + EPSF);
}

__global__ __launch_bounds__(BLOCK, 7) void hurst_kernel(const float* __restrict__ x,
                                                         float* __restrict__ out) {
    __shared__ __align__(16) float row[TLEN];
    __shared__ __align__(16) float P4[TLEN / 4];
    __shared__ float rs_sum[NW];
    __shared__ float wred[8];

    const int tid = threadIdx.x;
    const int r = blockIdx.x;
    const int w = tid >> 6, l = tid & 63;

    // One coalesced HBM pass per row.
    const float4* src = (const float4*)(x + (size_t)r * TLEN);
    float4* dst = (float4*)row;
    #pragma unroll
    for (int i = 0; i < TLEN / 4 / BLOCK; ++i)
        dst[tid + i * BLOCK] = src[tid + i * BLOCK];
    if (tid < NW) rs_sum[tid] = 0.0f;
    __syncthreads();

    // ==== Phase B (merged): W=10 + P4 build. Thread t owns floats 20t..20t+19. ====
    {
        float total = 0.0f;
        float lp[5] = {0, 0, 0, 0, 0};
        float contrib = 0.0f;
        if (tid < 204) {
            const int b = tid * 20;
            const float4* p = (const float4*)(row + b);
            float4 q0 = p[0], q1 = p[1], q2 = p[2], q3 = p[3], q4 = p[4];
            float v[21] = {q0.x,q0.y,q0.z,q0.w, q1.x,q1.y,q1.z,q1.w,
                           q2.x,q2.y,q2.z,q2.w, q3.x,q3.y,q3.z,q3.w,
                           q4.x,q4.y,q4.z,q4.w, row[b + 20]};
            float c = 0.0f, s9 = 0.0f, s10 = 0.0f, s19 = 0.0f;
            #pragma unroll
            for (int j = 0; j < 20; ++j) {
                if ((j & 3) == 0) lp[j >> 2] = c;
                if (j == 9)  s9  = c;
                if (j == 10) s10 = c;
                if (j == 19) s19 = c;
                float d = v[j + 1] - v[j];
                c = fmaf(d, d, c);
            }
            total = c;
            contrib = w10_seg<0>(v, s9) + w10_seg<10>(v, s19 - s10);
        } else if (tid == 204) {
            const float4* p = (const float4*)(row + 4080);
            float4 q0 = p[0], q1 = p[1], q2 = p[2], q3 = p[3];
            float v[16] = {q0.x,q0.y,q0.z,q0.w, q1.x,q1.y,q1.z,q1.w,
                           q2.x,q2.y,q2.z,q2.w, q3.x,q3.y,q3.z,q3.w};
            float c = 0.0f, s9 = 0.0f;
            #pragma unroll
            for (int j = 0; j < 15; ++j) {
                if ((j & 3) == 0) lp[j >> 2] = c;
                if (j == 9) s9 = c;
                float d = v[j + 1] - v[j];
                c = fmaf(d, d, c);
            }
            total = c;
            contrib = w10_seg<0>(v, s9);
        }
        // Exclusive scan of totals across the block (20-float granularity).
        float incl = total;
        #pragma unroll
        for (int o = 1; o < 64; o <<= 1) {
            float u = __shfl_up(incl, o, 64);
            if (l >= o) incl += u;
        }
        if (l == 63) wred[w] = incl;
        // W=10 accumulate (independent of the scan).
        float a = wave_reduce_sum(contrib);
        if (l == 0) atomicAdd(&rs_sum[0], a);
        __syncthreads();
        float off = incl - total;
        #pragma unroll
        for (int w2 = 0; w2 < 4; ++w2)
            if (w2 < w) off += wred[w2];
        if (tid < 204) {
            const int h = tid * 5;
            #pragma unroll
            for (int c2 = 0; c2 < 5; ++c2) P4[h + c2] = off + lp[c2];
        } else if (tid == 204) {
            #pragma unroll
            for (int c2 = 0; c2 < 4; ++c2) P4[1020 + c2] = off + lp[c2];
        }
        __syncthreads();
    }

    // ================= wave phase (no __syncthreads inside) =================

    // All-wave passes:
    // W=56 (idx 3) pass1: segs 0..63, G=4.
    {
        float a = group_seg<56, 0, 4>(row, P4, tid >> 2, tid & 3);
        a = reduce_leaders<4>(a);
        if (l == 0) atomicAdd(&rs_sum[3], a);
    }
    // W=100 (idx 4) pass1: segs 0..31, G=8.
    {
        float a = group_seg<100, 0, 8>(row, P4, tid >> 3, tid & 7);
        a = reduce_leaders<8>(a);
        if (l == 0) atomicAdd(&rs_sum[4], a);
    }
    // W=177 (idx 5): G=16; alignment class A = s&3 mapped per wave.
    {
        const int g4 = (tid >> 4) & 3, gl16 = tid & 15;
        float a = 0.0f;
        if (w == 0) {
            a = group_seg<177, 0, 16>(row, P4, 4 * g4, gl16);
            if (g4 < 2) a += group_seg<177, 0, 16>(row, P4, 4 * (g4 + 4), gl16);
        } else if (w == 1) {
            a = group_seg<177, 1, 16>(row, P4, 4 * g4 + 1, gl16);
            if (g4 < 2) a += group_seg<177, 1, 16>(row, P4, 4 * (g4 + 4) + 1, gl16);
        } else if (w == 2) {
            a = group_seg<177, 2, 16>(row, P4, 4 * g4 + 2, gl16);
            if (g4 < 2) a += group_seg<177, 2, 16>(row, P4, 4 * (g4 + 4) + 2, gl16);
        } else {
            a = group_seg<177, 3, 16>(row, P4, 4 * g4 + 3, gl16);
            if (g4 < 1) a += group_seg<177, 3, 16>(row, P4, 4 * (g4 + 4) + 3, gl16);
        }
        a = reduce_leaders<16>(a);
        if (l == 0) atomicAdd(&rs_sum[5], a);
    }

    // Per-wave extras (balanced):
    if (w == 0) {
        // W=17 (idx 1): 60 4-seg tasks.
        float a = (l < 60) ? mseg_task_a<17, 4, 0>(row, P4, l * 68) : 0.0f;
        a = wave_reduce_sum(a);
        if (l == 0) atomicAdd(&rs_sum[1], a);
        // W=316 (idx 6) segs 4..11: two G=16 passes.
        float c1 = group_seg<316, 0, 16>(row, P4, 4 + ((l >> 4) & 3), l & 15);
        c1 += group_seg<316, 0, 16>(row, P4, 8 + ((l >> 4) & 3), l & 15);
        c1 = reduce_leaders<16>(c1);
        if (l == 0) atomicAdd(&rs_sum[6], c1);
        // W=100 pass2: segs 32..39, G=8.
        float c2 = group_seg<100, 0, 8>(row, P4, 32 + (l >> 3), l & 7);
        c2 = reduce_leaders<8>(c2);
        if (l == 0) atomicAdd(&rs_sum[4], c2);
    } else if (w == 1) {
        // W=31 (idx 2) even tasks: 33 2-seg tasks, aligned (BP=0).
        float a = (l < 33) ? mseg_task_a<31, 2, 0>(row, P4, 124 * l) : 0.0f;
        a = wave_reduce_sum(a);
        if (l == 0) atomicAdd(&rs_sum[2], a);
        // W=562 (idx 7) odd segs {1,3}: A=2, G=32.
        float c1 = group_seg<562, 2, 32>(row, P4, 1 + 2 * (l >> 5), l & 31);
        c1 = reduce_leaders<32>(c1);
        if (l == 0) atomicAdd(&rs_sum[7], c1);
        // W=56 pass2: segs 64..72 (9), G=4.
        float c2 = ((l >> 2) < 9) ? group_seg<56, 0, 4>(row, P4, 64 + (l >> 2), l & 3) : 0.0f;
        c2 = reduce_leaders<4>(c2);
        if (l == 0) atomicAdd(&rs_sum[3], c2);
    } else if (w == 2) {
        // W=31 odd tasks: 33 2-seg tasks, base = 124m + 62 (BP=2).
        float a = (l < 33) ? mseg_task_a<31, 2, 2>(row, P4, 124 * l + 62) : 0.0f;
        a = wave_reduce_sum(a);
        if (l == 0) atomicAdd(&rs_sum[2], a);
        // W=1000 (idx 8) segs {0,1}: G=32.
        float c1 = group_seg<1000, 0, 32>(row, P4, l >> 5, l & 31);
        c1 = reduce_leaders<32>(c1);
        if (l == 0) atomicAdd(&rs_sum[8], c1);
    } else {
        // W=562 even segs {0,2} and {4,6}: A=0, G=32.
        float c1 = group_seg<562, 0, 32>(row, P4, 2 * (l >> 5), l & 31);
        c1 += group_seg<562, 0, 32>(row, P4, 4 + 2 * (l >> 5), l & 31);
        // W=562 seg {5}: A=2, lanes 0..31.
        float c2 = (l < 32) ? group_seg<562, 2, 32>(row, P4, 5, l & 31) : 0.0f;
        c1 += c2;
        c1 = reduce_leaders<32>(c1);
        if (l == 0) atomicAdd(&rs_sum[7], c1);
        // W=1000 segs {2,3}: G=32.
        float c3 = group_seg<1000, 0, 32>(row, P4, 2 + (l >> 5), l & 31);
        c3 = reduce_leaders<32>(c3);
        if (l == 0) atomicAdd(&rs_sum[8], c3);
        // W=316 segs 0..3: one G=16 pass.
        float c4 = group_seg<316, 0, 16>(row, P4, (l >> 4) & 3, l & 15);
        c4 = reduce_leaders<16>(c4);
        if (l == 0) atomicAdd(&rs_sum[6], c4);
    }

    // ================= block phase =================

    // W=1778 (idx 9): waves {0,1} -> seg0 (A=0), waves {2,3} -> seg1 (A=2).
    {
        const int half = tid >> 7, hl = tid & 127;
        const int b = half ? 1778 : 0;
        float m = (row[b + 1777] - row[b]) * (1.0f / 1777.0f);
        float nm = -m, mx, mn;
        if (half == 0) seg_strided_pk<1778, 0, 128>(row, 0,    hl, nm, mx, mn);
        else           seg_strided_pk<1778, 2, 128>(row, 1778, hl, nm, mx, mn);
        #pragma unroll
        for (int o = 32; o > 0; o >>= 1) {
            mx = fmaxf(mx, __shfl_xor(mx, o, 64));
            mn = fminf(mn, __shfl_xor(mn, o, 64));
        }
        if (l == 0) { wred[w * 2] = mx; wred[w * 2 + 1] = mn; }
        __syncthreads();
        if ((tid & 127) == 0) {
            const int wb = tid >> 6;  // 0 or 2
            float MX = fmaxf(wred[wb * 2],     wred[wb * 2 + 2]);
            float MN = fminf(wred[wb * 2 + 1], wred[wb * 2 + 3]);
            float v;
            if (tid == 0) v = seg_rs2<0, 1>(row, P4, 0,    1778, m, 1.0f / 1776.0f, MX, MN);
            else          v = seg_rs2<2, 3>(row, P4, 1778, 1778, m, 1.0f / 1776.0f, MX, MN);
            atomicAdd(&rs_sum[9], v);
        }
        __syncthreads();
    }
    // W=3162 (idx 10): whole block, 1 segment.
    {
        float m = (row[3161] - row[0]) * (1.0f / 3161.0f);
        float nm = -m, mx, mn;
        seg_strided_pk<3162, 0, 256>(row, 0, tid, nm, mx, mn);
        #pragma unroll
        for (int o = 32; o > 0; o >>= 1) {
            mx = fmaxf(mx, __shfl_xor(mx, o, 64));
            mn = fminf(mn, __shfl_xor(mn, o, 64));
        }
        if (l == 0) { wred[w * 2] = mx; wred[w * 2 + 1] = mn; }
        __syncthreads();
        if (tid == 0) {
            float MX = fmaxf(fmaxf(wred[0], wred[2]), fmaxf(wred[4], wred[6]));
            float MN = fminf(fminf(wred[1], wred[3]), fminf(wred[5], wred[7]));
            atomicAdd(&rs_sum[10],
                      seg_rs2<0, 1>(row, P4, 0, 3162, m, 1.0f / 3160.0f, MX, MN));
        }
        __syncthreads();
    }
    // W=4096 (idx 11): whole block, 1 segment.
    {
        float m = (row[4095] - row[0]) * (1.0f / 4095.0f);
        float nm = -m, mx, mn;
        seg_strided_pk<4096, 0, 256>(row, 0, tid, nm, mx, mn);
        #pragma unroll
        for (int o = 32; o > 0; o >>= 1) {
            mx = fmaxf(mx, __shfl_xor(mx, o, 64));
            mn = fminf(mn, __shfl_xor(mn, o, 64));
        }
        if (l == 0) { wred[w * 2] = mx; wred[w * 2 + 1] = mn; }
        __syncthreads();
        if (tid == 0) {
            float MX = fmaxf(fmaxf(wred[0], wred[2]), fmaxf(wred[4], wred[6]));
            float MN = fminf(fminf(wred[1], wred[3]), fminf(wred[5], wred[7]));
            atomicAdd(&rs_sum[11],
                      seg_rs2<0, 3>(row, P4, 0, 4096, m, 1.0f / 4094.0f, MX, MN));
        }
        __syncthreads();
    }

    // ================= epilogue =================
    if (tid < 64) {
        float t = 0.0f;
        if (tid < NW) {
            float rs = fmaf(rs_sum[tid], INVN_TAB[tid], EPSF);
            t = __builtin_amdgcn_logf(rs) * (LOG10_2) * XC_TAB[tid];
        }
        t = wave_reduce_sum(t);
        if (tid == 0) {
            float h = t * INV_DEN;
            if (!isfinite(h)) h = 1.0f;
            out[r] = h;
        }
    }
}

extern "C" void kernel_launch(void* const* d_in, const int* in_sizes, int n_in,
                              void* d_out, int out_size, void* d_ws, size_t ws_size,
                              hipStream_t stream) {
    const float* x = (const float*)d_in[0];
    float* out = (float*)d_out;
    const int B = out_size;  // 8192 rows
    hipLaunchKernelGGL(hurst_kernel, dim3(B), dim3(BLOCK), 0, stream, x, out);
}

// Round 7
// 86.959 us; speedup vs baseline: 2.2618x; 1.0038x over previous
//
#include <hip/hip_runtime.h>
#include <math.h>
#include <utility>

#define TLEN 4096
#define NW   12
#define BLOCK 256
#define EPSF 1e-6f

typedef float v2f __attribute__((ext_vector_type(2)));

// Centered log10(w+1e-6) values (sum = 0) and 1/n_segments, precomputed in double.
__device__ const float XC_TAB[NW] = {
    -1.3608041f, -1.1303552f, -0.8694424f, -0.6126161f,
    -0.3608041f, -0.1128308f,  0.1388830f,  0.3889322f,
     0.6391959f,  0.8891277f,  1.1391578f,  1.2515558f };
__device__ const float INVN_TAB[NW] = {
    1.0f/409.0f, 1.0f/240.0f, 1.0f/132.0f, 1.0f/73.0f,
    1.0f/40.0f,  1.0f/23.0f,  1.0f/12.0f,  1.0f/7.0f,
    0.25f, 0.5f, 1.0f, 1.0f };
#define INV_DEN 0.11577579f
#define LOG10_2 0.30102999566f

__device__ __forceinline__ float max3f(float a, float b, float c) {
    float r; asm("v_max3_f32 %0, %1, %2, %3" : "=v"(r) : "v"(a), "v"(b), "v"(c)); return r;
}
__device__ __forceinline__ float min3f(float a, float b, float c) {
    float r; asm("v_min3_f32 %0, %1, %2, %3" : "=v"(r) : "v"(a), "v"(b), "v"(c)); return r;
}
__device__ __forceinline__ v2f pk_fma(v2f a, v2f b, v2f c) {
    v2f d; asm("v_pk_fma_f32 %0, %1, %2, %3" : "=v"(d) : "v"(a), "v"(b), "v"(c)); return d;
}
__device__ __forceinline__ v2f pk_add(v2f a, v2f b) {
    v2f d; asm("v_pk_add_f32 %0, %1, %2" : "=v"(d) : "v"(a), "v"(b)); return d;
}

__device__ __forceinline__ float wave_reduce_sum(float v) {
    #pragma unroll
    for (int o = 32; o > 0; o >>= 1) v += __shfl_xor(v, o, 64);
    return v;
}
template<int G>
__device__ __forceinline__ float reduce_leaders(float v) {
    #pragma unroll
    for (int o = G; o < 64; o <<= 1) v += __shfl_xor(v, o, 64);
    return v;
}

// R/S for one segment; P4[e] = P[4e], prefix of squared adjacent diffs.
// FLO = b&3, FHI = (b+W-1)&3, both compile-time at every call site.
template<int FLO, int FHI>
__device__ __forceinline__ float seg_rs2(const float* __restrict__ row,
                                         const float* __restrict__ P4,
                                         int b, int W, float m, float invwm2,
                                         float mx, float mn) {
    float plo = P4[b >> 2];
    if constexpr (FLO > 0) {
        const int k0 = b - FLO;
        #pragma unroll
        for (int t = 0; t < FLO; ++t) {
            float d = row[k0 + t + 1] - row[k0 + t];
            plo = fmaf(d, d, plo);
        }
    }
    const int e = b + W - 1;
    float phi = P4[e >> 2];
    if constexpr (FHI > 0) {
        const int k0 = e - FHI;
        #pragma unroll
        for (int t = 0; t < FHI; ++t) {
            float d = row[k0 + t + 1] - row[k0 + t];
            phi = fmaf(d, d, phi);
        }
    }
    float ss  = phi - plo;
    float var = fmaf(-(float)(W - 1) * m, m, ss) * invwm2;
    float S   = __builtin_amdgcn_sqrtf(fmaxf(var, 0.0f));
    return (mx - mn) * __builtin_amdgcn_rcpf(S + EPSF);
}

// Fold slots LO..HI of chunk q (j of slot s = JB + s, compile-time) into mx/mn.
template<int LO, int HI, int JB>
__device__ __forceinline__ void chunk_fold(const float4 q, float nm, float& mx, float& mn) {
    if constexpr (LO <= HI) {
        constexpr int NV = HI - LO + 1;
        float v[NV];
        #pragma unroll
        for (int r = 0; r < NV; ++r)
            v[r] = fmaf((float)(JB + LO + r), nm, (&q.x)[LO + r]);
        if constexpr (NV == 1) { mx = fmaxf(mx, v[0]); mn = fminf(mn, v[0]); }
        else if constexpr (NV == 2) { mx = max3f(mx, v[0], v[1]); mn = min3f(mn, v[0], v[1]); }
        else if constexpr (NV == 3) { mx = fmaxf(mx, max3f(v[0], v[1], v[2]));
                                      mn = fminf(mn, min3f(v[0], v[1], v[2])); }
        else { mx = max3f(max3f(mx, v[0], v[1]), v[2], v[3]);
               mn = min3f(min3f(mn, v[0], v[1]), v[2], v[3]); }
    }
}

// ---- Multi-segment tasks with base parity BP (true base b, b&3 == BP) ----
template<int W, int NSEG, int BP, int C>
__device__ __forceinline__ void mchunk_stepA(const float4* __restrict__ p,
                                             const float (&nm)[NSEG],
                                             float (&mx)[NSEG], float (&mn)[NSEG]) {
    float4 q = p[C];
    if constexpr (C == 0 && BP > 0) {
        chunk_fold<BP + 1, 3, -BP>(q, nm[0], mx[0], mn[0]);
    } else {
        constexpr int E0 = 4 * C - BP;
        constexpr int K0 = E0 / W;
        constexpr int SA = K0 * W;
        constexpr int LOA = (SA == E0) ? 1 : 0;
        constexpr int HIA1 = SA + W - 1 - E0;
        constexpr int HIA2 = NSEG * W - 1 - E0;
        constexpr int HIA = (3 < HIA1 ? (3 < HIA2 ? 3 : HIA2) : (HIA1 < HIA2 ? HIA1 : HIA2));
        if constexpr (K0 < NSEG)
            chunk_fold<LOA, HIA, E0 - SA>(q, nm[K0], mx[K0], mn[K0]);
        constexpr int SB = SA + W;
        constexpr bool HASB = (K0 + 1 < NSEG) && (SB + 1 - E0 <= 3);
        if constexpr (HASB) {
            constexpr int HIB2 = NSEG * W - 1 - E0;
            constexpr int HIB = (3 < HIB2 ? 3 : HIB2);
            chunk_fold<SB + 1 - E0, HIB, E0 - SB>(q, nm[K0 + 1], mx[K0 + 1], mn[K0 + 1]);
        }
    }
}

template<int W, int NSEG, int BP, int... Cs>
__device__ __forceinline__ void mseg_allA(const float4* __restrict__ p,
                                          const float (&nm)[NSEG],
                                          float (&mx)[NSEG], float (&mn)[NSEG],
                                          std::integer_sequence<int, Cs...>) {
    (mchunk_stepA<W, NSEG, BP, Cs>(p, nm, mx, mn), ...);
}

template<int W, int NSEG, int BP, int... Ks>
__device__ __forceinline__ float mseg_rs_allA(const float* __restrict__ row,
                                              const float* __restrict__ P4, int b,
                                              const float (&m)[NSEG],
                                              const float (&mx)[NSEG], const float (&mn)[NSEG],
                                              std::integer_sequence<int, Ks...>) {
    constexpr float invwm2 = 1.0f / (float)(W - 2);
    float acc = 0.0f;
    ((acc += seg_rs2<(BP + W * Ks) & 3, (BP + W * Ks + W - 1) & 3>(
          row, P4, b + Ks * W, W, m[Ks], invwm2, mx[Ks], mn[Ks])), ...);
    return acc;
}

template<int W, int NSEG, int BP>
__device__ __forceinline__ float mseg_task_a(const float* __restrict__ row,
                                             const float* __restrict__ P4, int b) {
    constexpr int NCH = (BP + W * NSEG + 3) / 4;
    const float4* p = (const float4*)(row + b - BP);
    float nm[NSEG], m[NSEG], mx[NSEG], mn[NSEG];
    #pragma unroll
    for (int k = 0; k < NSEG; ++k) {
        float a0 = row[b + k * W];
        float a1 = row[b + k * W + W - 1];
        m[k] = (a1 - a0) * (1.0f / (float)(W - 1));
        nm[k] = -m[k];
        mx[k] = -INFINITY; mn[k] = INFINITY;
    }
    mseg_allA<W, NSEG, BP>(p, nm, mx, mn, std::make_integer_sequence<int, NCH>{});
    return mseg_rs_allA<W, NSEG, BP>(row, P4, b, m, mx, mn,
                                     std::make_integer_sequence<int, NSEG>{});
}

// ---- Packed strided single-segment bulk with batched loads ----
template<int W, int A, int G>
__device__ __forceinline__ void seg_strided_pk(const float* __restrict__ row, int b, int lane,
                                               float nm, float& mx, float& mn) {
    constexpr int NCH  = (A + W - 1) / 4 + 1;
    constexpr int HIL  = (A + W - 1) & 3;
    constexpr int MAIN_END = (HIL == 3) ? NCH : NCH - 1;
    constexpr int NFULL = MAIN_END - 1;
    constexpr int FULL  = NFULL / G;
    constexpr int REM   = NFULL % G;
    constexpr int NB    = FULL + (REM > 0 ? 1 : 0);
    const float4* p  = (const float4*)(row + (b - A));
    const float4* pl = p + (1 + lane);
    float4 qs[NB > 0 ? NB : 1];
    #pragma unroll
    for (int i = 0; i < FULL; ++i) qs[i] = pl[i * G];
    if constexpr (REM > 0) { if (lane < REM) qs[FULL] = pl[FULL * G]; }
    mx = -INFINITY; mn = INFINITY;
    v2f jc; jc.x = (float)(4 * (1 + lane) - A); jc.y = jc.x + 1.0f;
    const v2f nm2   = {nm, nm};
    const v2f nm2x2 = {nm + nm, nm + nm};
    const v2f step  = {(float)(4 * G), (float)(4 * G)};
    #pragma unroll
    for (int i = 0; i < FULL; ++i) {
        float4 q = qs[i];
        v2f q01 = {q.x, q.y}, q23 = {q.z, q.w};
        v2f t01 = pk_fma(jc, nm2, q01);
        v2f t23 = pk_fma(jc, nm2, pk_add(q23, nm2x2));
        mx = max3f(max3f(mx, t01.x, t01.y), t23.x, t23.y);
        mn = min3f(min3f(mn, t01.x, t01.y), t23.x, t23.y);
        jc = pk_add(jc, step);
    }
    if constexpr (REM > 0) {
        if (lane < REM) {
            float4 q = qs[FULL];
            v2f q01 = {q.x, q.y}, q23 = {q.z, q.w};
            v2f t01 = pk_fma(jc, nm2, q01);
            v2f t23 = pk_fma(jc, nm2, pk_add(q23, nm2x2));
            mx = max3f(max3f(mx, t01.x, t01.y), t23.x, t23.y);
            mn = min3f(min3f(mn, t01.x, t01.y), t23.x, t23.y);
        }
    }
    if constexpr (A < 3) {
        if (lane == 0) chunk_fold<A + 1, 3, -A>(p[0], nm, mx, mn);
    }
    if constexpr (HIL != 3) {
        if (lane == 1) chunk_fold<0, HIL, 4 * (NCH - 1) - A>(p[NCH - 1], nm, mx, mn);
    }
}

template<int W, int A, int G>
__device__ __forceinline__ float group_seg(const float* __restrict__ row,
                                           const float* __restrict__ P4,
                                           int s, int lane) {
    const int b = s * W;
    float a0 = row[b], a1 = row[b + W - 1];
    float m = (a1 - a0) * (1.0f / (float)(W - 1));
    float nm = -m;
    float mx, mn;
    seg_strided_pk<W, A, G>(row, b, lane, nm, mx, mn);
    #pragma unroll
    for (int o = G / 2; o > 0; o >>= 1) {
        mx = fmaxf(mx, __shfl_xor(mx, o, G));
        mn = fminf(mn, __shfl_xor(mn, o, G));
    }
    float r = seg_rs2<A, (A + W - 1) & 3>(
        row, P4, b, W, m, 1.0f / (float)(W - 2), mx, mn);
    return (lane == 0) ? r : 0.0f;
}

// One W=10 segment from a 10-value register array; ss = sum of its 9 squared diffs.
__device__ __forceinline__ float w10_seg10(const float (&v)[10], float ss) {
    const float m = (v[9] - v[0]) * (1.0f / 9.0f), nm = -m;
    float x1 = fmaf(1.0f, nm, v[1]);
    float x2 = fmaf(2.0f, nm, v[2]);
    float x3 = fmaf(3.0f, nm, v[3]);
    float x4 = fmaf(4.0f, nm, v[4]);
    float x5 = fmaf(5.0f, nm, v[5]);
    float x6 = fmaf(6.0f, nm, v[6]);
    float x7 = fmaf(7.0f, nm, v[7]);
    float x8 = fmaf(8.0f, nm, v[8]);
    float x9 = fmaf(9.0f, nm, v[9]);
    float mx = max3f(x1, x2, x3);
    mx = max3f(mx, x4, x5); mx = max3f(mx, x6, x7); mx = max3f(mx, x8, x9);
    float mn = min3f(x1, x2, x3);
    mn = min3f(mn, x4, x5); mn = min3f(mn, x6, x7); mn = min3f(mn, x8, x9);
    float var = fmaf(-9.0f * m, m, ss) * 0.125f;
    float S = __builtin_amdgcn_sqrtf(fmaxf(var, 0.0f));
    return (mx - mn) * __builtin_amdgcn_rcpf(S + EPSF);
}

__global__ __launch_bounds__(BLOCK, 7) void hurst_kernel(const float* __restrict__ x,
                                                         float* __restrict__ out) {
    __shared__ __align__(16) float row[TLEN];
    __shared__ __align__(16) float P4[TLEN / 4];
    __shared__ float rs_sum[NW];
    __shared__ float wred[8];

    const int tid = threadIdx.x;
    const int r = blockIdx.x;
    const int w = tid >> 6, l = tid & 63;

    // One coalesced HBM pass per row.
    const float4* src = (const float4*)(x + (size_t)r * TLEN);
    float4* dst = (float4*)row;
    #pragma unroll
    for (int i = 0; i < TLEN / 4 / BLOCK; ++i)
        dst[tid + i * BLOCK] = src[tid + i * BLOCK];
    if (tid < NW) rs_sum[tid] = 0.0f;
    __syncthreads();

    // ==== Phase B (merged, low-register): W=10 + P4 build. Thread t owns 20t..20t+19. ====
    {
        float lp1 = 0.0f, lp2 = 0.0f, lp3 = 0.0f, lp4 = 0.0f;  // P snapshots at j=4,8,12,16
        float total = 0.0f;
        float contrib = 0.0f;
        if (tid < 205) {
            const int b = tid * 20;
            const float4* p = (const float4*)(row + b);
            // ---- half 1: elements 0..11 (q0..q2) ----
            float4 q0 = p[0], q1 = p[1], q2 = p[2];
            float v[12] = {q0.x,q0.y,q0.z,q0.w, q1.x,q1.y,q1.z,q1.w,
                           q2.x,q2.y,q2.z,q2.w};
            float c = 0.0f, s9 = 0.0f;
            #pragma unroll
            for (int j = 0; j < 10; ++j) {
                if (j == 4) lp1 = c;
                if (j == 8) lp2 = c;
                if (j == 9) s9 = c;
                float d = v[j + 1] - v[j];
                c = fmaf(d, d, c);
            }
            {
                float a1[10] = {v[0],v[1],v[2],v[3],v[4],v[5],v[6],v[7],v[8],v[9]};
                contrib = w10_seg10(a1, s9);
            }
            const float s10 = c;                 // P[b+10]
            const float v10 = v[10], v11 = v[11];
            float d10 = v11 - v10;
            c = fmaf(d10, d10, c);               // P[b+11]
            if (tid < 204) {
                // ---- half 2: elements 12..20 (q3,q4 + first of next chunk) ----
                float4 q3 = p[3], q4 = p[4];
                float u[8] = {q3.x,q3.y,q3.z,q3.w, q4.x,q4.y,q4.z,q4.w};
                float vlast = row[b + 20];
                float d11 = u[0] - v11;
                c = fmaf(d11, d11, c);           // P[b+12]
                lp3 = c;
                float s19 = 0.0f;
                #pragma unroll
                for (int j = 12; j < 20; ++j) {
                    if (j == 16) lp4 = c;
                    if (j == 19) s19 = c;
                    float nxt = (j + 1 < 20) ? u[j - 11] : vlast;
                    float d = nxt - u[j - 12];
                    c = fmaf(d, d, c);
                }
                float a2[10] = {v10, v11, u[0],u[1],u[2],u[3],u[4],u[5],u[6],u[7]};
                contrib += w10_seg10(a2, s19 - s10);
                total = c;                       // P[b+20]
            } else {
                // tid == 204: elements 12..15 only (q3); diffs d11..d14.
                float4 q3 = p[3];
                float d11 = q3.x - v11;
                c = fmaf(d11, d11, c);           // P[4092]... relative P[12]
                lp3 = c;
                float d12 = q3.y - q3.x; c = fmaf(d12, d12, c);
                float d13 = q3.z - q3.y; c = fmaf(d13, d13, c);
                float d14 = q3.w - q3.z; c = fmaf(d14, d14, c);
                total = c;                       // P[4095] relative
            }
        }
        // Exclusive scan of totals across the block (20-float granularity).
        float incl = total;
        #pragma unroll
        for (int o = 1; o < 64; o <<= 1) {
            float u = __shfl_up(incl, o, 64);
            if (l >= o) incl += u;
        }
        if (l == 63) wred[w] = incl;
        // W=10 accumulate (independent of the scan).
        float a = wave_reduce_sum(contrib);
        if (l == 0) atomicAdd(&rs_sum[0], a);
        __syncthreads();
        float off = incl - total;
        #pragma unroll
        for (int w2 = 0; w2 < 4; ++w2)
            if (w2 < w) off += wred[w2];
        if (tid < 204) {
            const int h = tid * 5;
            P4[h]     = off;
            P4[h + 1] = off + lp1;
            P4[h + 2] = off + lp2;
            P4[h + 3] = off + lp3;
            P4[h + 4] = off + lp4;
        } else if (tid == 204) {
            P4[1020] = off;
            P4[1021] = off + lp1;
            P4[1022] = off + lp2;
            P4[1023] = off + lp3;
        }
        __syncthreads();
    }

    // ================= wave phase (no __syncthreads inside) =================

    // All-wave passes:
    // W=56 (idx 3) pass1: segs 0..63, G=4.
    {
        float a = group_seg<56, 0, 4>(row, P4, tid >> 2, tid & 3);
        a = reduce_leaders<4>(a);
        if (l == 0) atomicAdd(&rs_sum[3], a);
    }
    // W=100 (idx 4) pass1: segs 0..31, G=8.
    {
        float a = group_seg<100, 0, 8>(row, P4, tid >> 3, tid & 7);
        a = reduce_leaders<8>(a);
        if (l == 0) atomicAdd(&rs_sum[4], a);
    }
    // W=177 (idx 5): G=16; alignment class A = s&3 mapped per wave.
    {
        const int g4 = (tid >> 4) & 3, gl16 = tid & 15;
        float a = 0.0f;
        if (w == 0) {
            a = group_seg<177, 0, 16>(row, P4, 4 * g4, gl16);
            if (g4 < 2) a += group_seg<177, 0, 16>(row, P4, 4 * (g4 + 4), gl16);
        } else if (w == 1) {
            a = group_seg<177, 1, 16>(row, P4, 4 * g4 + 1, gl16);
            if (g4 < 2) a += group_seg<177, 1, 16>(row, P4, 4 * (g4 + 4) + 1, gl16);
        } else if (w == 2) {
            a = group_seg<177, 2, 16>(row, P4, 4 * g4 + 2, gl16);
            if (g4 < 2) a += group_seg<177, 2, 16>(row, P4, 4 * (g4 + 4) + 2, gl16);
        } else {
            a = group_seg<177, 3, 16>(row, P4, 4 * g4 + 3, gl16);
            if (g4 < 1) a += group_seg<177, 3, 16>(row, P4, 4 * (g4 + 4) + 3, gl16);
        }
        a = reduce_leaders<16>(a);
        if (l == 0) atomicAdd(&rs_sum[5], a);
    }

    // Per-wave extras (balanced):
    if (w == 0) {
        // W=17 (idx 1): 60 4-seg tasks.
        float a = (l < 60) ? mseg_task_a<17, 4, 0>(row, P4, l * 68) : 0.0f;
        a = wave_reduce_sum(a);
        if (l == 0) atomicAdd(&rs_sum[1], a);
        // W=316 (idx 6) segs 4..11: two G=16 passes.
        float c1 = group_seg<316, 0, 16>(row, P4, 4 + ((l >> 4) & 3), l & 15);
        c1 += group_seg<316, 0, 16>(row, P4, 8 + ((l >> 4) & 3), l & 15);
        c1 = reduce_leaders<16>(c1);
        if (l == 0) atomicAdd(&rs_sum[6], c1);
        // W=100 pass2: segs 32..39, G=8.
        float c2 = group_seg<100, 0, 8>(row, P4, 32 + (l >> 3), l & 7);
        c2 = reduce_leaders<8>(c2);
        if (l == 0) atomicAdd(&rs_sum[4], c2);
    } else if (w == 1) {
        // W=31 (idx 2) even tasks: 33 2-seg tasks, aligned (BP=0).
        float a = (l < 33) ? mseg_task_a<31, 2, 0>(row, P4, 124 * l) : 0.0f;
        a = wave_reduce_sum(a);
        if (l == 0) atomicAdd(&rs_sum[2], a);
        // W=562 (idx 7) odd segs {1,3}: A=2, G=32.
        float c1 = group_seg<562, 2, 32>(row, P4, 1 + 2 * (l >> 5), l & 31);
        c1 = reduce_leaders<32>(c1);
        if (l == 0) atomicAdd(&rs_sum[7], c1);
        // W=56 pass2: segs 64..72 (9), G=4.
        float c2 = ((l >> 2) < 9) ? group_seg<56, 0, 4>(row, P4, 64 + (l >> 2), l & 3) : 0.0f;
        c2 = reduce_leaders<4>(c2);
        if (l == 0) atomicAdd(&rs_sum[3], c2);
    } else if (w == 2) {
        // W=31 odd tasks: 33 2-seg tasks, base = 124m + 62 (BP=2).
        float a = (l < 33) ? mseg_task_a<31, 2, 2>(row, P4, 124 * l + 62) : 0.0f;
        a = wave_reduce_sum(a);
        if (l == 0) atomicAdd(&rs_sum[2], a);
        // W=1000 (idx 8) segs {0,1}: G=32.
        float c1 = group_seg<1000, 0, 32>(row, P4, l >> 5, l & 31);
        c1 = reduce_leaders<32>(c1);
        if (l == 0) atomicAdd(&rs_sum[8], c1);
    } else {
        // W=562 even segs {0,2} and {4,6}: A=0, G=32.
        float c1 = group_seg<562, 0, 32>(row, P4, 2 * (l >> 5), l & 31);
        c1 += group_seg<562, 0, 32>(row, P4, 4 + 2 * (l >> 5), l & 31);
        // W=562 seg {5}: A=2, lanes 0..31.
        float c2 = (l < 32) ? group_seg<562, 2, 32>(row, P4, 5, l & 31) : 0.0f;
        c1 += c2;
        c1 = reduce_leaders<32>(c1);
        if (l == 0) atomicAdd(&rs_sum[7], c1);
        // W=1000 segs {2,3}: G=32.
        float c3 = group_seg<1000, 0, 32>(row, P4, 2 + (l >> 5), l & 31);
        c3 = reduce_leaders<32>(c3);
        if (l == 0) atomicAdd(&rs_sum[8], c3);
        // W=316 segs 0..3: one G=16 pass.
        float c4 = group_seg<316, 0, 16>(row, P4, (l >> 4) & 3, l & 15);
        c4 = reduce_leaders<16>(c4);
        if (l == 0) atomicAdd(&rs_sum[6], c4);
    }

    // ================= block phase =================

    // W=1778 (idx 9): waves {0,1} -> seg0 (A=0), waves {2,3} -> seg1 (A=2).
    {
        const int half = tid >> 7, hl = tid & 127;
        const int b = half ? 1778 : 0;
        float m = (row[b + 1777] - row[b]) * (1.0f / 1777.0f);
        float nm = -m, mx, mn;
        if (half == 0) seg_strided_pk<1778, 0, 128>(row, 0,    hl, nm, mx, mn);
        else           seg_strided_pk<1778, 2, 128>(row, 1778, hl, nm, mx, mn);
        #pragma unroll
        for (int o = 32; o > 0; o >>= 1) {
            mx = fmaxf(mx, __shfl_xor(mx, o, 64));
            mn = fminf(mn, __shfl_xor(mn, o, 64));
        }
        if (l == 0) { wred[w * 2] = mx; wred[w * 2 + 1] = mn; }
        __syncthreads();
        if ((tid & 127) == 0) {
            const int wb = tid >> 6;  // 0 or 2
            float MX = fmaxf(wred[wb * 2],     wred[wb * 2 + 2]);
            float MN = fminf(wred[wb * 2 + 1], wred[wb * 2 + 3]);
            float v;
            if (tid == 0) v = seg_rs2<0, 1>(row, P4, 0,    1778, m, 1.0f / 1776.0f, MX, MN);
            else          v = seg_rs2<2, 3>(row, P4, 1778, 1778, m, 1.0f / 1776.0f, MX, MN);
            atomicAdd(&rs_sum[9], v);
        }
        __syncthreads();
    }
    // W=3162 (idx 10): whole block, 1 segment.
    {
        float m = (row[3161] - row[0]) * (1.0f / 3161.0f);
        float nm = -m, mx, mn;
        seg_strided_pk<3162, 0, 256>(row, 0, tid, nm, mx, mn);
        #pragma unroll
        for (int o = 32; o > 0; o >>= 1) {
            mx = fmaxf(mx, __shfl_xor(mx, o, 64));
            mn = fminf(mn, __shfl_xor(mn, o, 64));
        }
        if (l == 0) { wred[w * 2] = mx; wred[w * 2 + 1] = mn; }
        __syncthreads();
        if (tid == 0) {
            float MX = fmaxf(fmaxf(wred[0], wred[2]), fmaxf(wred[4], wred[6]));
            float MN = fminf(fminf(wred[1], wred[3]), fminf(wred[5], wred[7]));
            atomicAdd(&rs_sum[10],
                      seg_rs2<0, 1>(row, P4, 0, 3162, m, 1.0f / 3160.0f, MX, MN));
        }
        __syncthreads();
    }
    // W=4096 (idx 11): whole block, 1 segment.
    {
        float m = (row[4095] - row[0]) * (1.0f / 4095.0f);
        float nm = -m, mx, mn;
        seg_strided_pk<4096, 0, 256>(row, 0, tid, nm, mx, mn);
        #pragma unroll
        for (int o = 32; o > 0; o >>= 1) {
            mx = fmaxf(mx, __shfl_xor(mx, o, 64));
            mn = fminf(mn, __shfl_xor(mn, o, 64));
        }
        if (l == 0) { wred[w * 2] = mx; wred[w * 2 + 1] = mn; }
        __syncthreads();
        if (tid == 0) {
            float MX = fmaxf(fmaxf(wred[0], wred[2]), fmaxf(wred[4], wred[6]));
            float MN = fminf(fminf(wred[1], wred[3]), fminf(wred[5], wred[7]));
            atomicAdd(&rs_sum[11],
                      seg_rs2<0, 3>(row, P4, 0, 4096, m, 1.0f / 4094.0f, MX, MN));
        }
        __syncthreads();
    }

    // ================= epilogue =================
    if (tid < 64) {
        float t = 0.0f;
        if (tid < NW) {
            float rs = fmaf(rs_sum[tid], INVN_TAB[tid], EPSF);
            t = __builtin_amdgcn_logf(rs) * (LOG10_2) * XC_TAB[tid];
        }
        t = wave_reduce_sum(t);
        if (tid == 0) {
            float h = t * INV_DEN;
            if (!isfinite(h)) h = 1.0f;
            out[r] = h;
        }
    }
}

extern "C" void kernel_launch(void* const* d_in, const int* in_sizes, int n_in,
                              void* d_out, int out_size, void* d_ws, size_t ws_size,
                              hipStream_t stream) {
    const float* x = (const float*)d_in[0];
    float* out = (float*)d_out;
    const int B = out_size;  // 8192 rows
    hipLaunchKernelGGL(hurst_kernel, dim3(B), dim3(BLOCK), 0, stream, x, out);
}